// Round 17
// baseline (247.682 us; speedup 1.0000x reference)
//
#include <hip/hip_runtime.h>
#include <hip/hip_bf16.h>
#include <math.h>

typedef __attribute__((ext_vector_type(8))) short short8;
typedef __attribute__((ext_vector_type(4))) float f32x4;

constexpr int B_ = 8, H_ = 96, W_ = 160;
constexpr int HW_ = H_ * W_;
constexpr int NPIX = B_ * HW_;        // 122880

__device__ __forceinline__ unsigned short f2bf(float f) {
    unsigned int u = __builtin_bit_cast(unsigned int, f);
    u += 0x7FFFu + ((u >> 16) & 1u);          // RNE
    return (unsigned short)(u >> 16);
}
__device__ __forceinline__ float bf2f(unsigned short s) {
    unsigned int u = ((unsigned int)s) << 16;
    return __builtin_bit_cast(float, u);
}
__device__ __forceinline__ unsigned int cvt_pk_bf16(float lo, float hi) {
    unsigned int r;
    asm volatile("v_cvt_pk_bf16_f32 %0, %1, %2" : "=v"(r) : "v"(lo), "v"(hi));
    return r;   // D[15:0]=bf16(lo), D[31:16]=bf16(hi)
}
__device__ __forceinline__ float f4get(const float4& v, int q) {
    switch (q) { case 0: return v.x; case 1: return v.y;
                 case 2: return v.z; default: return v.w; }
}
// XCD-bijective swizzle for 960-block conv grids (960 = 8*120)
__device__ __forceinline__ int swz960(int bid) {
    return (bid & 7) * 120 + (bid >> 3);
}

// ---------------------------------------------------------------------------
// Prep 1: concat inputs -> octet-planar bf16 X1[c8][NPIX][8], c8 = 0..27.
// ---------------------------------------------------------------------------
__global__ __launch_bounds__(256) void prep_x1(
    const float* __restrict__ cfw, const float* __restrict__ fpro,
    const float* __restrict__ fprv, const float* __restrict__ f1,
    const float* __restrict__ f2, unsigned short* __restrict__ X1)
{
    const int c8 = blockIdx.y;
    const int pix0 = blockIdx.x * 1024 + threadIdx.x * 4;   // grid.x = NPIX/1024
    unsigned short* dst = X1 + ((size_t)c8 * NPIX + pix0) * 8;

    if (c8 >= 25) {   // channels 200..223 are all zero
        uint4 z = {0u, 0u, 0u, 0u};
        #pragma unroll
        for (int q = 0; q < 4; ++q) *(uint4*)(dst + q * 8) = z;
        return;
    }

    const int b  = pix0 / HW_;          // 1024 | HW_, no batch crossing
    const int hw = pix0 - b * HW_;

    float4 v[8];
    #pragma unroll
    for (int j = 0; j < 8; ++j) {
        int c = c8 * 8 + j;
        const float* src = nullptr; int sc = 0, nc = 0;
        if (c < 64)       { src = cfw;  sc = c;       nc = 64; }
        else if (c < 128) { src = fpro; sc = c - 64;  nc = 64; }
        else if (c < 192) { src = fprv; sc = c - 128; nc = 64; }
        else if (c < 194) { src = f1;   sc = c - 192; nc = 2;  }
        else if (c < 196) { src = f2;   sc = c - 194; nc = 2;  }
        if (src) v[j] = *(const float4*)(src + ((size_t)b * nc + sc) * HW_ + hw);
        else     { v[j].x = v[j].y = v[j].z = v[j].w = 0.f; }
    }
    #pragma unroll
    for (int q = 0; q < 4; ++q) {
        uint4 o;
        o.x = cvt_pk_bf16(f4get(v[0], q), f4get(v[1], q));
        o.y = cvt_pk_bf16(f4get(v[2], q), f4get(v[3], q));
        o.z = cvt_pk_bf16(f4get(v[4], q), f4get(v[5], q));
        o.w = cvt_pk_bf16(f4get(v[6], q), f4get(v[7], q));
        *(uint4*)(dst + q * 8) = o;
    }
}

// ---------------------------------------------------------------------------
// Prep 2 (merged): ALL weight packs in ONE dispatch.
// ---------------------------------------------------------------------------
__device__ __forceinline__ void pack_conv_w(
    const float* __restrict__ w, unsigned short* __restrict__ Bt, int idx,
    int Cin, int KCH, int Nout, int NFTOT)
{
    int lane = idx & 63;
    int r = idx >> 6;
    int nf = r % NFTOT; r /= NFTOT;
    int ck = r % KCH;
    int t  = r / KCH;
    int n  = nf * 16 + (lane & 15);
    int kb = ck * 32 + (lane >> 4) * 8;
    short8 o;
    #pragma unroll
    for (int j = 0; j < 8; ++j) {
        int c = kb + j;
        float v = (c < Cin && n < Nout) ? w[((size_t)n * Cin + c) * 9 + t] : 0.f;
        o[j] = (short)f2bf(v);
    }
    *(short8*)(Bt + (size_t)idx * 8) = o;
}

__global__ __launch_bounds__(256) void prep_wall(
    const float* __restrict__ w1, const float* __restrict__ w2,
    const float* __restrict__ w3, const float* __restrict__ w4,
    const float* __restrict__ wd,
    unsigned short* __restrict__ Bt1, unsigned short* __restrict__ Bt2,
    unsigned short* __restrict__ Bt3, unsigned short* __restrict__ Bt4,
    unsigned short* __restrict__ Btd)
{
    int idx = blockIdx.x * 256 + threadIdx.x;
    if (idx < 16128)      pack_conv_w(w1, Bt1, idx,          196, 7,  64,  4);
    else if (idx < 20736) pack_conv_w(w2, Bt2, idx - 16128,   64, 2,  64,  4);
    else if (idx < 25344) pack_conv_w(w3, Bt3, idx - 20736,   64, 2,  64,  4);
    else if (idx < 41472) pack_conv_w(w4, Bt4, idx - 25344,   64, 2, 216, 14);
    else if (idx < 47616) {
        int id2 = idx - 41472;
        int lane = id2 & 63;
        int r = id2 >> 6;
        int nf = r % 4; r >>= 2;
        int ck = r % 3;
        int g  = r / 3;
        int n  = nf * 16 + (lane & 15);             // oc
        int kb = ck * 32 + (lane >> 4) * 8;
        short8 o;
        #pragma unroll
        for (int j = 0; j < 8; ++j) {
            int k = kb + j;
            int t = k >> 3, c = k & 7;
            float v = (t < 9) ? wd[((size_t)n * 64 + g * 8 + c) * 9 + t] : 0.f;
            o[j] = (short)f2bf(v);
        }
        *(short8*)(Btd + (size_t)id2 * 8) = o;
    }
}

// ---------------------------------------------------------------------------
// MFMA implicit-GEMM 3x3 conv, pad=1 (128-px blocks, wave = 32 px, triplet
// B-staging with 3 named prefetch regs) + XCD swizzle. (round-16 known good)
// ---------------------------------------------------------------------------
template<int KCH, int NFTOT, int NF, bool RELU>
__global__ __launch_bounds__(256) void conv_mfma(
    const unsigned short* __restrict__ X, const unsigned short* __restrict__ Bt,
    const float* __restrict__ bias, unsigned short* __restrict__ Y,
    int CoutTot, int fBase0)
{
    static_assert(NF == 4, "staging assumes 4 KB per tap chunk");
    __shared__ __align__(16) unsigned short bsh[3 * 2048];   // 12 KB

    const int tid  = threadIdx.x;
    const int lane = tid & 63;
    const int wv   = tid >> 6;
    const int m0   = swz960(blockIdx.x) * 128 + wv * 32;
    const int fBase = fBase0 + blockIdx.y * NF;
    const int lm = lane & 15;
    const int l16 = lane >> 4;

    int p[2], hh[2], wp[2];
    #pragma unroll
    for (int mf = 0; mf < 2; ++mf) {
        int pm = m0 + mf * 16 + lm;
        p[mf] = pm;
        hh[mf] = (pm / W_) % H_;
        wp[mf] = pm % W_;
    }

    f32x4 acc[2][NF];
    #pragma unroll
    for (int nf = 0; nf < NF; ++nf) {
        int oc = (fBase + nf) * 16 + lm;
        float bv = (oc < CoutTot) ? bias[oc] : 0.f;
        f32x4 a = {bv, bv, bv, bv};
        acc[0][nf] = a; acc[1][nf] = a;
    }

    const short8 zero = {0,0,0,0,0,0,0,0};
    constexpr int S3 = KCH * 3;          // triplet count

    uint4 bta = *(const uint4*)(Bt + ((size_t)(0 * KCH) * NFTOT + fBase) * 512 + tid * 8);
    uint4 btb = *(const uint4*)(Bt + ((size_t)(1 * KCH) * NFTOT + fBase) * 512 + tid * 8);
    uint4 btc = *(const uint4*)(Bt + ((size_t)(2 * KCH) * NFTOT + fBase) * 512 + tid * 8);

    for (int s3 = 0; s3 < S3; ++s3) {
        const int ck = s3 / 3, tb = (s3 % 3) * 3;
        __syncthreads();
        *(uint4*)(bsh + 0 * 2048 + tid * 8) = bta;
        *(uint4*)(bsh + 1 * 2048 + tid * 8) = btb;
        *(uint4*)(bsh + 2 * 2048 + tid * 8) = btc;
        __syncthreads();
        if (s3 + 1 < S3) {
            const int ck2 = (s3 + 1) / 3, tb2 = ((s3 + 1) % 3) * 3;
            bta = *(const uint4*)(Bt + ((size_t)((tb2 + 0) * KCH + ck2) * NFTOT + fBase) * 512 + tid * 8);
            btb = *(const uint4*)(Bt + ((size_t)((tb2 + 1) * KCH + ck2) * NFTOT + fBase) * 512 + tid * 8);
            btc = *(const uint4*)(Bt + ((size_t)((tb2 + 2) * KCH + ck2) * NFTOT + fBase) * 512 + tid * 8);
        }
        const unsigned short* Xp = X + (size_t)(ck * 4 + l16) * NPIX * 8;
        #pragma unroll
        for (int j = 0; j < 3; ++j) {
            const int t = tb + j;
            const int di = t / 3 - 1, dj = t % 3 - 1;
            short8 bfr[NF];
            #pragma unroll
            for (int nf = 0; nf < NF; ++nf)
                bfr[nf] = *(const short8*)(bsh + j * 2048 + nf * 512 + lane * 8);
            #pragma unroll
            for (int mf = 0; mf < 2; ++mf) {
                bool val = ((unsigned)(hh[mf] + di) < (unsigned)H_) &&
                           ((unsigned)(wp[mf] + dj) < (unsigned)W_);
                const unsigned short* ap = Xp + (size_t)(p[mf] + di * W_ + dj) * 8;
                short8 afr = val ? *(const short8*)ap : zero;
                #pragma unroll
                for (int nf = 0; nf < NF; ++nf)
                    acc[mf][nf] = __builtin_amdgcn_mfma_f32_16x16x32_bf16(
                        afr, bfr[nf], acc[mf][nf], 0, 0, 0);
            }
        }
    }

    const int prow = l16 * 4;
    #pragma unroll
    for (int mf = 0; mf < 2; ++mf)
        #pragma unroll
        for (int nf = 0; nf < NF; ++nf) {
            int oc = (fBase + nf) * 16 + lm;
            if (oc < CoutTot) {
                #pragma unroll
                for (int r = 0; r < 4; ++r) {
                    int pix = m0 + mf * 16 + prow + r;
                    float v = acc[mf][nf][r];
                    if (RELU) v = (v >= 0.f) ? v : 0.1f * v;
                    Y[((size_t)(oc >> 3) * NPIX + pix) * 8 + (oc & 7)] = f2bf(v);
                }
            }
        }
}

// ---------------------------------------------------------------------------
// conv4: ONE dispatch, grid (960, 2); FB = blockIdx.y*7. + XCD swizzle.
// (round-16 known good)
// ---------------------------------------------------------------------------
__global__ __launch_bounds__(256, 4) void conv4_mfma(
    const unsigned short* __restrict__ X, const unsigned short* __restrict__ Bt,
    const float* __restrict__ bias,
    unsigned short* __restrict__ oY, unsigned short* __restrict__ oX,
    unsigned short* __restrict__ oM)
{
    __shared__ __align__(16) unsigned short bsh[7 * 512];   // 7168 B

    const int tid  = threadIdx.x;
    const int lane = tid & 63;
    const int wv   = tid >> 6;
    const int pix0 = swz960(blockIdx.x) * 128;
    const int m0   = pix0 + wv * 32;
    const int lm = lane & 15;
    const int l16 = lane >> 4;
    const int FB = blockIdx.y * 7;         // frag base (block-uniform)

    int p[2], hh[2], wp[2];
    #pragma unroll
    for (int mf = 0; mf < 2; ++mf) {
        int pm = m0 + mf * 16 + lm;
        p[mf] = pm;
        hh[mf] = (pm / W_) % H_;
        wp[mf] = pm % W_;
    }

    f32x4 acc[2][7];
    #pragma unroll
    for (int nf = 0; nf < 7; ++nf) {
        int oc = (FB + nf) * 16 + lm;
        float bv = (oc < 216) ? bias[oc] : 0.f;
        f32x4 a = {bv, bv, bv, bv};
        acc[0][nf] = a; acc[1][nf] = a;
    }

    const short8 zero = {0,0,0,0,0,0,0,0};
    const bool two = (tid < 192);

    uint4 bt0 = *(const uint4*)(Bt + (size_t)FB * 512 + tid * 8);
    uint4 bt1 = {0u, 0u, 0u, 0u};
    if (two) bt1 = *(const uint4*)(Bt + (size_t)FB * 512 + (256 + tid) * 8);

    #pragma unroll
    for (int s = 0; s < 18; ++s) {
        const int ck = s / 9, t = s % 9;
        __syncthreads();
        *(uint4*)(bsh + tid * 8) = bt0;
        if (two) *(uint4*)(bsh + (256 + tid) * 8) = bt1;
        __syncthreads();
        if (s + 1 < 18) {
            const int ck2 = (s + 1) / 9, t2 = (s + 1) % 9;
            const unsigned short* nb =
                Bt + ((size_t)((t2 * 2 + ck2) * 14 + FB)) * 512;
            bt0 = *(const uint4*)(nb + tid * 8);
            if (two) bt1 = *(const uint4*)(nb + (256 + tid) * 8);
        }
        const int di = t / 3 - 1, dj = t % 3 - 1;
        const unsigned short* Xp = X + (size_t)(ck * 4 + l16) * NPIX * 8;
        short8 afr[2];
        #pragma unroll
        for (int mf = 0; mf < 2; ++mf) {
            bool val = ((unsigned)(hh[mf] + di) < (unsigned)H_) &&
                       ((unsigned)(wp[mf] + dj) < (unsigned)W_);
            const unsigned short* ap = Xp + (size_t)(p[mf] + di * W_ + dj) * 8;
            afr[mf] = val ? *(const short8*)ap : zero;
        }
        #pragma unroll
        for (int nf = 0; nf < 7; ++nf) {
            short8 bfr = *(const short8*)(bsh + nf * 512 + lane * 8);
            acc[0][nf] = __builtin_amdgcn_mfma_f32_16x16x32_bf16(
                afr[0], bfr, acc[0][nf], 0, 0, 0);
            acc[1][nf] = __builtin_amdgcn_mfma_f32_16x16x32_bf16(
                afr[1], bfr, acc[1][nf], 0, 0, 0);
        }
    }

    const int prow = l16 * 4;
    #pragma unroll
    for (int mf = 0; mf < 2; ++mf) {
        const int pixb = m0 + mf * 16 + prow;      // 4 consecutive pixels
        #pragma unroll
        for (int nf = 0; nf < 7; ++nf) {
            const int nfg = FB + nf;               // block-uniform
            const int oc = nfg * 16 + lm;
            if (nfg < 9) {
                const int pr = nfg * 8 + (lm >> 1);
                unsigned short* plane = ((lm & 1) ? oX : oY) + (size_t)pr * NPIX;
                uint2 sv;
                sv.x = cvt_pk_bf16(acc[mf][nf][0], acc[mf][nf][1]);
                sv.y = cvt_pk_bf16(acc[mf][nf][2], acc[mf][nf][3]);
                *(uint2*)(plane + pixb) = sv;
            } else if (oc < 216) {
                const int mi = (nfg - 9) * 16 + lm;
                float v0 = 1.f / (1.f + expf(-acc[mf][nf][0]));
                float v1 = 1.f / (1.f + expf(-acc[mf][nf][1]));
                float v2 = 1.f / (1.f + expf(-acc[mf][nf][2]));
                float v3 = 1.f / (1.f + expf(-acc[mf][nf][3]));
                uint2 sv;
                sv.x = cvt_pk_bf16(v0, v1);
                sv.y = cvt_pk_bf16(v2, v3);
                *(uint2*)(oM + (size_t)mi * NPIX + pixb) = sv;
            }
        }
    }
}

// ---------------------------------------------------------------------------
// Fused deformable conv — 64-px blocks, 256 threads. v17: wave tiling 2x2
// (wave = 32 px x 32 oc; wr = wv>>1 picks px half, wc = wv&1 oc half).
// Halves LDS A-reads vs round-12's 64px-per-wave (48 vs 96 ds_read_b128 /
// wave; bank conflicts should drop ~2x). Sampling phase unchanged.
// ---------------------------------------------------------------------------
__global__ __launch_bounds__(256) void deform_mfma(
    const unsigned short* __restrict__ Xg,   // [8][NPIX][8] bf16 planes (X1)
    const unsigned short* __restrict__ oY,   // [72][NPIX] bf16 raw dy
    const unsigned short* __restrict__ oX,   // [72][NPIX] bf16 raw dx
    const unsigned short* __restrict__ oM,   // [72][NPIX] bf16 sigmoid(mask)
    const float* __restrict__ f1, const float* __restrict__ f2,
    const unsigned short* __restrict__ Btd,  // [8][3][4][64][8] bf16
    const float* __restrict__ bia,           // 64
    float* __restrict__ out)                 // B,64,H,W fp32 NCHW
{
    __shared__ __align__(16) char lds[64 * 256];   // 16384 B

    const int tid  = threadIdx.x;             // 0..255
    const int lane = tid & 63;
    const int wv   = tid >> 6;                // 0..3
    const int wr   = wv >> 1;                 // px half
    const int wc   = wv & 1;                  // oc half
    const int lm   = lane & 15;
    const int l16  = lane >> 4;
    const int pix0 = blockIdx.x * 64;
    const int b    = pix0 / HW_;
    const int hw0  = pix0 % HW_;

    const int pix = tid & 63;
    const int hw  = hw0 + pix;
    const int h   = hw / W_;
    const int w   = hw - h * W_;
    const size_t gp = (size_t)(pix0 + pix);
    const size_t bF = (size_t)b * 2 * HW_;

    {
        uint4 z = {0u, 0u, 0u, 0u};
        #pragma unroll
        for (int i = 0; i < 4; ++i)
            ((uint4*)lds)[i * 256 + tid] = z;
    }

    f32x4 acc[2][2];         // [mf][nf]: wave's 32px x 32oc tile
    #pragma unroll
    for (int nf = 0; nf < 2; ++nf) {
        float bv = bia[wc * 32 + nf * 16 + lm];
        f32x4 a = {bv, bv, bv, bv};
        acc[0][nf] = a; acc[1][nf] = a;
    }

    for (int g = 0; g < 8; ++g) {
        const unsigned short* Xp = Xg + (size_t)g * NPIX * 8;
        __syncthreads();   // prev group's MFMA reads done (also covers zero-init)

        // ---- phase A: flow (once) + plane loads for taps (independent) ----
        const float* fl = (g < 4) ? f1 : f2;
        const float fy = fl[bF + (size_t)HW_ + hw];
        const float fx = fl[bF + hw];
        unsigned short uy[3], ux[3], um[3];
        #pragma unroll
        for (int it = 0; it < 3; ++it) {
            int t = wv + 4 * it;
            bool act = (it < 2) || (wv == 0);
            if (act) {
                size_t po = (size_t)(g * 9 + t) * NPIX + gp;
                uy[it] = oY[po]; ux[it] = oX[po]; um[it] = oM[po];
            }
        }
        // ---- phase B: bilinear gather + pack + LDS write, per tap ----
        #pragma unroll
        for (int it = 0; it < 3; ++it) {
            int t = wv + 4 * it;
            bool act = (it < 2) || (wv == 0);
            if (act) {
                float dy = bf2f(uy[it]) + fy;
                float dx = bf2f(ux[it]) + fx;
                float m  = bf2f(um[it]);

                float ys = dy + (float)(h - 1 + t / 3);
                float xs = dx + (float)(w - 1 + t % 3);
                float y0f = floorf(ys), x0f = floorf(xs);
                float wy1 = ys - y0f, wx1 = xs - x0f;
                float wy0 = 1.f - wy1, wx0 = 1.f - wx1;
                int iy0 = (int)y0f, ix0 = (int)x0f;
                int iy1 = iy0 + 1,  ix1 = ix0 + 1;
                bool vy0 = (unsigned)iy0 < (unsigned)H_;
                bool vy1 = (unsigned)iy1 < (unsigned)H_;
                bool vx0 = (unsigned)ix0 < (unsigned)W_;
                bool vx1 = (unsigned)ix1 < (unsigned)W_;
                int cy0 = min(max(iy0, 0), H_ - 1), cy1 = min(max(iy1, 0), H_ - 1);
                int cx0 = min(max(ix0, 0), W_ - 1), cx1 = min(max(ix1, 0), W_ - 1);
                float w00 = (vy0 && vx0) ? wy0 * wx0 * m : 0.f;
                float w01 = (vy0 && vx1) ? wy0 * wx1 * m : 0.f;
                float w10 = (vy1 && vx0) ? wy1 * wx0 * m : 0.f;
                float w11 = (vy1 && vx1) ? wy1 * wx1 * m : 0.f;

                size_t r0 = (size_t)b * HW_ + (size_t)cy0 * W_;
                size_t r1 = (size_t)b * HW_ + (size_t)cy1 * W_;
                uint4 c00 = *(const uint4*)(Xp + (r0 + cx0) * 8);
                uint4 c01 = *(const uint4*)(Xp + (r0 + cx1) * 8);
                uint4 c10 = *(const uint4*)(Xp + (r1 + cx0) * 8);
                uint4 c11 = *(const uint4*)(Xp + (r1 + cx1) * 8);

                float a8[8];
                #pragma unroll
                for (int i = 0; i < 8; ++i) a8[i] = 0.f;
                const unsigned int u00[4] = {c00.x, c00.y, c00.z, c00.w};
                const unsigned int u01[4] = {c01.x, c01.y, c01.z, c01.w};
                const unsigned int u10[4] = {c10.x, c10.y, c10.z, c10.w};
                const unsigned int u11[4] = {c11.x, c11.y, c11.z, c11.w};
                #pragma unroll
                for (int i = 0; i < 4; ++i) {
                    a8[2*i]   += w00 * __builtin_bit_cast(float, u00[i] << 16);
                    a8[2*i+1] += w00 * __builtin_bit_cast(float, u00[i] & 0xFFFF0000u);
                    a8[2*i]   += w01 * __builtin_bit_cast(float, u01[i] << 16);
                    a8[2*i+1] += w01 * __builtin_bit_cast(float, u01[i] & 0xFFFF0000u);
                    a8[2*i]   += w10 * __builtin_bit_cast(float, u10[i] << 16);
                    a8[2*i+1] += w10 * __builtin_bit_cast(float, u10[i] & 0xFFFF0000u);
                    a8[2*i]   += w11 * __builtin_bit_cast(float, u11[i] << 16);
                    a8[2*i+1] += w11 * __builtin_bit_cast(float, u11[i] & 0xFFFF0000u);
                }
                uint4 ov;
                ov.x = cvt_pk_bf16(a8[0], a8[1]);
                ov.y = cvt_pk_bf16(a8[2], a8[3]);
                ov.z = cvt_pk_bf16(a8[4], a8[5]);
                ov.w = cvt_pk_bf16(a8[6], a8[7]);
                int slot = t ^ (pix & 7);
                *(uint4*)(lds + pix * 256 + slot * 16) = ov;
            }
        }
        __syncthreads();
        // ---- MFMA: K=96; wave = 32 px (wr half) x 32 oc (wc half) ----
        #pragma unroll
        for (int ck = 0; ck < 3; ++ck) {
            short8 bfr[2];
            #pragma unroll
            for (int nf = 0; nf < 2; ++nf)
                bfr[nf] = ((const short8*)Btd)[
                    ((size_t)(g * 3 + ck) * 4 + wc * 2 + nf) * 64 + lane];
            const int slotbase = ck * 4 + l16;
            #pragma unroll
            for (int mf = 0; mf < 2; ++mf) {
                int row = wr * 32 + mf * 16 + lm;
                int slot = slotbase ^ (lm & 7);
                short8 afr = *(const short8*)(lds + row * 256 + slot * 16);
                #pragma unroll
                for (int nf = 0; nf < 2; ++nf)
                    acc[mf][nf] = __builtin_amdgcn_mfma_f32_16x16x32_bf16(
                        afr, bfr[nf], acc[mf][nf], 0, 0, 0);
            }
        }
    }

    // ---- epilogue: direct float4 stores (4 consecutive px of one oc) ----
    #pragma unroll
    for (int mf = 0; mf < 2; ++mf)
        #pragma unroll
        for (int nf = 0; nf < 2; ++nf) {
            int oc = wc * 32 + nf * 16 + lm;
            int px = hw0 + wr * 32 + mf * 16 + l16 * 4;
            *(f32x4*)(out + (size_t)(b * 64 + oc) * HW_ + px) = acc[mf][nf];
        }
}

// ---------------------------------------------------------------------------
extern "C" void kernel_launch(void* const* d_in, const int* in_sizes, int n_in,
                              void* d_out, int out_size, void* d_ws, size_t ws_size,
                              hipStream_t stream)
{
    const float* cfw  = (const float*)d_in[0];
    const float* fpro = (const float*)d_in[1];
    const float* fprv = (const float*)d_in[2];
    const float* fl1  = (const float*)d_in[3];
    const float* fl2  = (const float*)d_in[4];
    const float* w1   = (const float*)d_in[5];
    const float* b1   = (const float*)d_in[6];
    const float* w2   = (const float*)d_in[7];
    const float* b2   = (const float*)d_in[8];
    const float* w3   = (const float*)d_in[9];
    const float* b3   = (const float*)d_in[10];
    const float* w4   = (const float*)d_in[11];
    const float* b4   = (const float*)d_in[12];
    const float* wdef = (const float*)d_in[13];
    const float* bdef = (const float*)d_in[14];
    float* out = (float*)d_out;

    // ---- workspace layout (bytes) ----
    char* ws = (char*)d_ws;
    unsigned short* X1  = (unsigned short*)(ws);
    unsigned short* buf1= (unsigned short*)(ws + 55050240);   // o1 / o3
    unsigned short* o2  = (unsigned short*)(ws + 70778880);   // dead after conv3
    unsigned short* oY  = (unsigned short*)(ws + 70778880);   // clobbers o2 (OK)
    unsigned short* oX  = oY + (size_t)72 * NPIX;
    unsigned short* oM  = oX + (size_t)72 * NPIX;
    unsigned short* Bt1 = (unsigned short*)(ws + 125829120);
    unsigned short* Bt2 = (unsigned short*)(ws + 125829120 + 258048);
    unsigned short* Bt3 = (unsigned short*)(ws + 125829120 + 258048 + 73728);
    unsigned short* Bt4 = (unsigned short*)(ws + 125829120 + 258048 + 2*73728);
    unsigned short* Btd = (unsigned short*)(ws + 125829120 + 2*258048 + 2*73728);

    prep_x1<<<dim3(NPIX / 1024, 28), dim3(256), 0, stream>>>(
        cfw, fpro, fprv, fl1, fl2, X1);
    prep_wall<<<dim3((47616 + 255) / 256), dim3(256), 0, stream>>>(
        w1, w2, w3, w4, wdef, Bt1, Bt2, Bt3, Bt4, Btd);

    dim3 blk(256);
    dim3 gridM(NPIX / 128, 1);
    // conv1: X1(196) -> o1 (buf1), lrelu
    conv_mfma<7, 4, 4, true><<<gridM, blk, 0, stream>>>(X1, Bt1, b1, buf1, 64, 0);
    // conv2: o1 (buf1) -> o2, lrelu
    conv_mfma<2, 4, 4, true><<<gridM, blk, 0, stream>>>(buf1, Bt2, b2, o2, 64, 0);
    // conv3: o2 -> o3 (buf1, o1 dead), lrelu
    conv_mfma<2, 4, 4, true><<<gridM, blk, 0, stream>>>(o2, Bt3, b3, buf1, 64, 0);
    // conv4: o3 (buf1) -> channel-planar oY/oX/oM, ONE dispatch (y = half)
    conv4_mfma<<<dim3(NPIX / 128, 2), blk, 0, stream>>>(buf1, Bt4, b4, oY, oX, oM);
    // fused deformable conv: 64-px blocks, 256 threads, 2x2 wave tiling
    deform_mfma<<<dim3(NPIX / 64), blk, 0, stream>>>(
        X1, oY, oX, oM, fl1, fl2, Btd, bdef, out);
}

// Round 18
// 241.922 us; speedup vs baseline: 1.0238x; 1.0238x over previous
//
#include <hip/hip_runtime.h>
#include <hip/hip_bf16.h>
#include <math.h>

typedef __attribute__((ext_vector_type(8))) short short8;
typedef __attribute__((ext_vector_type(4))) float f32x4;

constexpr int B_ = 8, H_ = 96, W_ = 160;
constexpr int HW_ = H_ * W_;
constexpr int NPIX = B_ * HW_;        // 122880

__device__ __forceinline__ unsigned short f2bf(float f) {
    unsigned int u = __builtin_bit_cast(unsigned int, f);
    u += 0x7FFFu + ((u >> 16) & 1u);          // RNE
    return (unsigned short)(u >> 16);
}
__device__ __forceinline__ float bf2f(unsigned short s) {
    unsigned int u = ((unsigned int)s) << 16;
    return __builtin_bit_cast(float, u);
}
__device__ __forceinline__ unsigned int cvt_pk_bf16(float lo, float hi) {
    unsigned int r;
    asm volatile("v_cvt_pk_bf16_f32 %0, %1, %2" : "=v"(r) : "v"(lo), "v"(hi));
    return r;   // D[15:0]=bf16(lo), D[31:16]=bf16(hi)
}
__device__ __forceinline__ float f4get(const float4& v, int q) {
    switch (q) { case 0: return v.x; case 1: return v.y;
                 case 2: return v.z; default: return v.w; }
}
// XCD-bijective swizzle for 960-block conv grids (960 = 8*120)
__device__ __forceinline__ int swz960(int bid) {
    return (bid & 7) * 120 + (bid >> 3);
}

// ---------------------------------------------------------------------------
// Prep 1: concat inputs -> octet-planar bf16 X1[c8][NPIX][8], c8 = 0..27.
// ---------------------------------------------------------------------------
__global__ __launch_bounds__(256) void prep_x1(
    const float* __restrict__ cfw, const float* __restrict__ fpro,
    const float* __restrict__ fprv, const float* __restrict__ f1,
    const float* __restrict__ f2, unsigned short* __restrict__ X1)
{
    const int c8 = blockIdx.y;
    const int pix0 = blockIdx.x * 1024 + threadIdx.x * 4;   // grid.x = NPIX/1024
    unsigned short* dst = X1 + ((size_t)c8 * NPIX + pix0) * 8;

    if (c8 >= 25) {   // channels 200..223 are all zero
        uint4 z = {0u, 0u, 0u, 0u};
        #pragma unroll
        for (int q = 0; q < 4; ++q) *(uint4*)(dst + q * 8) = z;
        return;
    }

    const int b  = pix0 / HW_;          // 1024 | HW_, no batch crossing
    const int hw = pix0 - b * HW_;

    float4 v[8];
    #pragma unroll
    for (int j = 0; j < 8; ++j) {
        int c = c8 * 8 + j;
        const float* src = nullptr; int sc = 0, nc = 0;
        if (c < 64)       { src = cfw;  sc = c;       nc = 64; }
        else if (c < 128) { src = fpro; sc = c - 64;  nc = 64; }
        else if (c < 192) { src = fprv; sc = c - 128; nc = 64; }
        else if (c < 194) { src = f1;   sc = c - 192; nc = 2;  }
        else if (c < 196) { src = f2;   sc = c - 194; nc = 2;  }
        if (src) v[j] = *(const float4*)(src + ((size_t)b * nc + sc) * HW_ + hw);
        else     { v[j].x = v[j].y = v[j].z = v[j].w = 0.f; }
    }
    #pragma unroll
    for (int q = 0; q < 4; ++q) {
        uint4 o;
        o.x = cvt_pk_bf16(f4get(v[0], q), f4get(v[1], q));
        o.y = cvt_pk_bf16(f4get(v[2], q), f4get(v[3], q));
        o.z = cvt_pk_bf16(f4get(v[4], q), f4get(v[5], q));
        o.w = cvt_pk_bf16(f4get(v[6], q), f4get(v[7], q));
        *(uint4*)(dst + q * 8) = o;
    }
}

// ---------------------------------------------------------------------------
// Prep 2 (merged): ALL weight packs in ONE dispatch.
// ---------------------------------------------------------------------------
__device__ __forceinline__ void pack_conv_w(
    const float* __restrict__ w, unsigned short* __restrict__ Bt, int idx,
    int Cin, int KCH, int Nout, int NFTOT)
{
    int lane = idx & 63;
    int r = idx >> 6;
    int nf = r % NFTOT; r /= NFTOT;
    int ck = r % KCH;
    int t  = r / KCH;
    int n  = nf * 16 + (lane & 15);
    int kb = ck * 32 + (lane >> 4) * 8;
    short8 o;
    #pragma unroll
    for (int j = 0; j < 8; ++j) {
        int c = kb + j;
        float v = (c < Cin && n < Nout) ? w[((size_t)n * Cin + c) * 9 + t] : 0.f;
        o[j] = (short)f2bf(v);
    }
    *(short8*)(Bt + (size_t)idx * 8) = o;
}

__global__ __launch_bounds__(256) void prep_wall(
    const float* __restrict__ w1, const float* __restrict__ w2,
    const float* __restrict__ w3, const float* __restrict__ w4,
    const float* __restrict__ wd,
    unsigned short* __restrict__ Bt1, unsigned short* __restrict__ Bt2,
    unsigned short* __restrict__ Bt3, unsigned short* __restrict__ Bt4,
    unsigned short* __restrict__ Btd)
{
    int idx = blockIdx.x * 256 + threadIdx.x;
    if (idx < 16128)      pack_conv_w(w1, Bt1, idx,          196, 7,  64,  4);
    else if (idx < 20736) pack_conv_w(w2, Bt2, idx - 16128,   64, 2,  64,  4);
    else if (idx < 25344) pack_conv_w(w3, Bt3, idx - 20736,   64, 2,  64,  4);
    else if (idx < 41472) pack_conv_w(w4, Bt4, idx - 25344,   64, 2, 216, 14);
    else if (idx < 47616) {
        int id2 = idx - 41472;
        int lane = id2 & 63;
        int r = id2 >> 6;
        int nf = r % 4; r >>= 2;
        int ck = r % 3;
        int g  = r / 3;
        int n  = nf * 16 + (lane & 15);             // oc
        int kb = ck * 32 + (lane >> 4) * 8;
        short8 o;
        #pragma unroll
        for (int j = 0; j < 8; ++j) {
            int k = kb + j;
            int t = k >> 3, c = k & 7;
            float v = (t < 9) ? wd[((size_t)n * 64 + g * 8 + c) * 9 + t] : 0.f;
            o[j] = (short)f2bf(v);
        }
        *(short8*)(Btd + (size_t)id2 * 8) = o;
    }
}

// ---------------------------------------------------------------------------
// MFMA implicit-GEMM 3x3 conv, pad=1 (128-px blocks, wave = 32 px, triplet
// B-staging with 3 named prefetch regs) + XCD swizzle. (round-16 known good)
// ---------------------------------------------------------------------------
template<int KCH, int NFTOT, int NF, bool RELU>
__global__ __launch_bounds__(256) void conv_mfma(
    const unsigned short* __restrict__ X, const unsigned short* __restrict__ Bt,
    const float* __restrict__ bias, unsigned short* __restrict__ Y,
    int CoutTot, int fBase0)
{
    static_assert(NF == 4, "staging assumes 4 KB per tap chunk");
    __shared__ __align__(16) unsigned short bsh[3 * 2048];   // 12 KB

    const int tid  = threadIdx.x;
    const int lane = tid & 63;
    const int wv   = tid >> 6;
    const int m0   = swz960(blockIdx.x) * 128 + wv * 32;
    const int fBase = fBase0 + blockIdx.y * NF;
    const int lm = lane & 15;
    const int l16 = lane >> 4;

    int p[2], hh[2], wp[2];
    #pragma unroll
    for (int mf = 0; mf < 2; ++mf) {
        int pm = m0 + mf * 16 + lm;
        p[mf] = pm;
        hh[mf] = (pm / W_) % H_;
        wp[mf] = pm % W_;
    }

    f32x4 acc[2][NF];
    #pragma unroll
    for (int nf = 0; nf < NF; ++nf) {
        int oc = (fBase + nf) * 16 + lm;
        float bv = (oc < CoutTot) ? bias[oc] : 0.f;
        f32x4 a = {bv, bv, bv, bv};
        acc[0][nf] = a; acc[1][nf] = a;
    }

    const short8 zero = {0,0,0,0,0,0,0,0};
    constexpr int S3 = KCH * 3;          // triplet count

    uint4 bta = *(const uint4*)(Bt + ((size_t)(0 * KCH) * NFTOT + fBase) * 512 + tid * 8);
    uint4 btb = *(const uint4*)(Bt + ((size_t)(1 * KCH) * NFTOT + fBase) * 512 + tid * 8);
    uint4 btc = *(const uint4*)(Bt + ((size_t)(2 * KCH) * NFTOT + fBase) * 512 + tid * 8);

    for (int s3 = 0; s3 < S3; ++s3) {
        const int ck = s3 / 3, tb = (s3 % 3) * 3;
        __syncthreads();
        *(uint4*)(bsh + 0 * 2048 + tid * 8) = bta;
        *(uint4*)(bsh + 1 * 2048 + tid * 8) = btb;
        *(uint4*)(bsh + 2 * 2048 + tid * 8) = btc;
        __syncthreads();
        if (s3 + 1 < S3) {
            const int ck2 = (s3 + 1) / 3, tb2 = ((s3 + 1) % 3) * 3;
            bta = *(const uint4*)(Bt + ((size_t)((tb2 + 0) * KCH + ck2) * NFTOT + fBase) * 512 + tid * 8);
            btb = *(const uint4*)(Bt + ((size_t)((tb2 + 1) * KCH + ck2) * NFTOT + fBase) * 512 + tid * 8);
            btc = *(const uint4*)(Bt + ((size_t)((tb2 + 2) * KCH + ck2) * NFTOT + fBase) * 512 + tid * 8);
        }
        const unsigned short* Xp = X + (size_t)(ck * 4 + l16) * NPIX * 8;
        #pragma unroll
        for (int j = 0; j < 3; ++j) {
            const int t = tb + j;
            const int di = t / 3 - 1, dj = t % 3 - 1;
            short8 bfr[NF];
            #pragma unroll
            for (int nf = 0; nf < NF; ++nf)
                bfr[nf] = *(const short8*)(bsh + j * 2048 + nf * 512 + lane * 8);
            #pragma unroll
            for (int mf = 0; mf < 2; ++mf) {
                bool val = ((unsigned)(hh[mf] + di) < (unsigned)H_) &&
                           ((unsigned)(wp[mf] + dj) < (unsigned)W_);
                const unsigned short* ap = Xp + (size_t)(p[mf] + di * W_ + dj) * 8;
                short8 afr = val ? *(const short8*)ap : zero;
                #pragma unroll
                for (int nf = 0; nf < NF; ++nf)
                    acc[mf][nf] = __builtin_amdgcn_mfma_f32_16x16x32_bf16(
                        afr, bfr[nf], acc[mf][nf], 0, 0, 0);
            }
        }
    }

    const int prow = l16 * 4;
    #pragma unroll
    for (int mf = 0; mf < 2; ++mf)
        #pragma unroll
        for (int nf = 0; nf < NF; ++nf) {
            int oc = (fBase + nf) * 16 + lm;
            if (oc < CoutTot) {
                #pragma unroll
                for (int r = 0; r < 4; ++r) {
                    int pix = m0 + mf * 16 + prow + r;
                    float v = acc[mf][nf][r];
                    if (RELU) v = (v >= 0.f) ? v : 0.1f * v;
                    Y[((size_t)(oc >> 3) * NPIX + pix) * 8 + (oc & 7)] = f2bf(v);
                }
            }
        }
}

// ---------------------------------------------------------------------------
// conv4: ONE dispatch, grid (960, 2); FB = blockIdx.y*7. + XCD swizzle.
// (round-16 known good)
// ---------------------------------------------------------------------------
__global__ __launch_bounds__(256, 4) void conv4_mfma(
    const unsigned short* __restrict__ X, const unsigned short* __restrict__ Bt,
    const float* __restrict__ bias,
    unsigned short* __restrict__ oY, unsigned short* __restrict__ oX,
    unsigned short* __restrict__ oM)
{
    __shared__ __align__(16) unsigned short bsh[7 * 512];   // 7168 B

    const int tid  = threadIdx.x;
    const int lane = tid & 63;
    const int wv   = tid >> 6;
    const int pix0 = swz960(blockIdx.x) * 128;
    const int m0   = pix0 + wv * 32;
    const int lm = lane & 15;
    const int l16 = lane >> 4;
    const int FB = blockIdx.y * 7;         // frag base (block-uniform)

    int p[2], hh[2], wp[2];
    #pragma unroll
    for (int mf = 0; mf < 2; ++mf) {
        int pm = m0 + mf * 16 + lm;
        p[mf] = pm;
        hh[mf] = (pm / W_) % H_;
        wp[mf] = pm % W_;
    }

    f32x4 acc[2][7];
    #pragma unroll
    for (int nf = 0; nf < 7; ++nf) {
        int oc = (FB + nf) * 16 + lm;
        float bv = (oc < 216) ? bias[oc] : 0.f;
        f32x4 a = {bv, bv, bv, bv};
        acc[0][nf] = a; acc[1][nf] = a;
    }

    const short8 zero = {0,0,0,0,0,0,0,0};
    const bool two = (tid < 192);

    uint4 bt0 = *(const uint4*)(Bt + (size_t)FB * 512 + tid * 8);
    uint4 bt1 = {0u, 0u, 0u, 0u};
    if (two) bt1 = *(const uint4*)(Bt + (size_t)FB * 512 + (256 + tid) * 8);

    #pragma unroll
    for (int s = 0; s < 18; ++s) {
        const int ck = s / 9, t = s % 9;
        __syncthreads();
        *(uint4*)(bsh + tid * 8) = bt0;
        if (two) *(uint4*)(bsh + (256 + tid) * 8) = bt1;
        __syncthreads();
        if (s + 1 < 18) {
            const int ck2 = (s + 1) / 9, t2 = (s + 1) % 9;
            const unsigned short* nb =
                Bt + ((size_t)((t2 * 2 + ck2) * 14 + FB)) * 512;
            bt0 = *(const uint4*)(nb + tid * 8);
            if (two) bt1 = *(const uint4*)(nb + (256 + tid) * 8);
        }
        const int di = t / 3 - 1, dj = t % 3 - 1;
        const unsigned short* Xp = X + (size_t)(ck * 4 + l16) * NPIX * 8;
        short8 afr[2];
        #pragma unroll
        for (int mf = 0; mf < 2; ++mf) {
            bool val = ((unsigned)(hh[mf] + di) < (unsigned)H_) &&
                       ((unsigned)(wp[mf] + dj) < (unsigned)W_);
            const unsigned short* ap = Xp + (size_t)(p[mf] + di * W_ + dj) * 8;
            afr[mf] = val ? *(const short8*)ap : zero;
        }
        #pragma unroll
        for (int nf = 0; nf < 7; ++nf) {
            short8 bfr = *(const short8*)(bsh + nf * 512 + lane * 8);
            acc[0][nf] = __builtin_amdgcn_mfma_f32_16x16x32_bf16(
                afr[0], bfr, acc[0][nf], 0, 0, 0);
            acc[1][nf] = __builtin_amdgcn_mfma_f32_16x16x32_bf16(
                afr[1], bfr, acc[1][nf], 0, 0, 0);
        }
    }

    const int prow = l16 * 4;
    #pragma unroll
    for (int mf = 0; mf < 2; ++mf) {
        const int pixb = m0 + mf * 16 + prow;      // 4 consecutive pixels
        #pragma unroll
        for (int nf = 0; nf < 7; ++nf) {
            const int nfg = FB + nf;               // block-uniform
            const int oc = nfg * 16 + lm;
            if (nfg < 9) {
                const int pr = nfg * 8 + (lm >> 1);
                unsigned short* plane = ((lm & 1) ? oX : oY) + (size_t)pr * NPIX;
                uint2 sv;
                sv.x = cvt_pk_bf16(acc[mf][nf][0], acc[mf][nf][1]);
                sv.y = cvt_pk_bf16(acc[mf][nf][2], acc[mf][nf][3]);
                *(uint2*)(plane + pixb) = sv;
            } else if (oc < 216) {
                const int mi = (nfg - 9) * 16 + lm;
                float v0 = 1.f / (1.f + expf(-acc[mf][nf][0]));
                float v1 = 1.f / (1.f + expf(-acc[mf][nf][1]));
                float v2 = 1.f / (1.f + expf(-acc[mf][nf][2]));
                float v3 = 1.f / (1.f + expf(-acc[mf][nf][3]));
                uint2 sv;
                sv.x = cvt_pk_bf16(v0, v1);
                sv.y = cvt_pk_bf16(v2, v3);
                *(uint2*)(oM + (size_t)mi * NPIX + pixb) = sv;
            }
        }
    }
}

// ---------------------------------------------------------------------------
// Fused deformable conv — 64-px blocks, 256 threads, wave = 16-oc slice x
// 64 px (round-12/16 known-good form: 44 VGPR, 67 us; 5 restructure attempts
// all >= this — latency-structural floor of this algorithm).
// ---------------------------------------------------------------------------
__global__ __launch_bounds__(256) void deform_mfma(
    const unsigned short* __restrict__ Xg,   // [8][NPIX][8] bf16 planes (X1)
    const unsigned short* __restrict__ oY,   // [72][NPIX] bf16 raw dy
    const unsigned short* __restrict__ oX,   // [72][NPIX] bf16 raw dx
    const unsigned short* __restrict__ oM,   // [72][NPIX] bf16 sigmoid(mask)
    const float* __restrict__ f1, const float* __restrict__ f2,
    const unsigned short* __restrict__ Btd,  // [8][3][4][64][8] bf16
    const float* __restrict__ bia,           // 64
    float* __restrict__ out)                 // B,64,H,W fp32 NCHW
{
    __shared__ __align__(16) char lds[64 * 256];   // 16384 B

    const int tid  = threadIdx.x;             // 0..255
    const int lane = tid & 63;
    const int wv   = tid >> 6;                // 0..3
    const int lm   = lane & 15;
    const int l16  = lane >> 4;
    const int pix0 = blockIdx.x * 64;
    const int b    = pix0 / HW_;
    const int hw0  = pix0 % HW_;

    const int pix = tid & 63;
    const int hw  = hw0 + pix;
    const int h   = hw / W_;
    const int w   = hw - h * W_;
    const size_t gp = (size_t)(pix0 + pix);
    const size_t bF = (size_t)b * 2 * HW_;

    {
        uint4 z = {0u, 0u, 0u, 0u};
        #pragma unroll
        for (int i = 0; i < 4; ++i)
            ((uint4*)lds)[i * 256 + tid] = z;
    }

    f32x4 acc[4];            // wave's 16-oc slice (oc = wv*16+lm), 64 px
    {
        float bv = bia[wv * 16 + lm];
        f32x4 a = {bv, bv, bv, bv};
        #pragma unroll
        for (int mf = 0; mf < 4; ++mf) acc[mf] = a;
    }

    for (int g = 0; g < 8; ++g) {
        const unsigned short* Xp = Xg + (size_t)g * NPIX * 8;
        __syncthreads();

        const float* fl = (g < 4) ? f1 : f2;
        const float fy = fl[bF + (size_t)HW_ + hw];
        const float fx = fl[bF + hw];
        unsigned short uy[3], ux[3], um[3];
        #pragma unroll
        for (int it = 0; it < 3; ++it) {
            int t = wv + 4 * it;
            bool act = (it < 2) || (wv == 0);
            if (act) {
                size_t po = (size_t)(g * 9 + t) * NPIX + gp;
                uy[it] = oY[po]; ux[it] = oX[po]; um[it] = oM[po];
            }
        }
        #pragma unroll
        for (int it = 0; it < 3; ++it) {
            int t = wv + 4 * it;
            bool act = (it < 2) || (wv == 0);
            if (act) {
                float dy = bf2f(uy[it]) + fy;
                float dx = bf2f(ux[it]) + fx;
                float m  = bf2f(um[it]);

                float ys = dy + (float)(h - 1 + t / 3);
                float xs = dx + (float)(w - 1 + t % 3);
                float y0f = floorf(ys), x0f = floorf(xs);
                float wy1 = ys - y0f, wx1 = xs - x0f;
                float wy0 = 1.f - wy1, wx0 = 1.f - wx1;
                int iy0 = (int)y0f, ix0 = (int)x0f;
                int iy1 = iy0 + 1,  ix1 = ix0 + 1;
                bool vy0 = (unsigned)iy0 < (unsigned)H_;
                bool vy1 = (unsigned)iy1 < (unsigned)H_;
                bool vx0 = (unsigned)ix0 < (unsigned)W_;
                bool vx1 = (unsigned)ix1 < (unsigned)W_;
                int cy0 = min(max(iy0, 0), H_ - 1), cy1 = min(max(iy1, 0), H_ - 1);
                int cx0 = min(max(ix0, 0), W_ - 1), cx1 = min(max(ix1, 0), W_ - 1);
                float w00 = (vy0 && vx0) ? wy0 * wx0 * m : 0.f;
                float w01 = (vy0 && vx1) ? wy0 * wx1 * m : 0.f;
                float w10 = (vy1 && vx0) ? wy1 * wx0 * m : 0.f;
                float w11 = (vy1 && vx1) ? wy1 * wx1 * m : 0.f;

                size_t r0 = (size_t)b * HW_ + (size_t)cy0 * W_;
                size_t r1 = (size_t)b * HW_ + (size_t)cy1 * W_;
                uint4 c00 = *(const uint4*)(Xp + (r0 + cx0) * 8);
                uint4 c01 = *(const uint4*)(Xp + (r0 + cx1) * 8);
                uint4 c10 = *(const uint4*)(Xp + (r1 + cx0) * 8);
                uint4 c11 = *(const uint4*)(Xp + (r1 + cx1) * 8);

                float a8[8];
                #pragma unroll
                for (int i = 0; i < 8; ++i) a8[i] = 0.f;
                const unsigned int u00[4] = {c00.x, c00.y, c00.z, c00.w};
                const unsigned int u01[4] = {c01.x, c01.y, c01.z, c01.w};
                const unsigned int u10[4] = {c10.x, c10.y, c10.z, c10.w};
                const unsigned int u11[4] = {c11.x, c11.y, c11.z, c11.w};
                #pragma unroll
                for (int i = 0; i < 4; ++i) {
                    a8[2*i]   += w00 * __builtin_bit_cast(float, u00[i] << 16);
                    a8[2*i+1] += w00 * __builtin_bit_cast(float, u00[i] & 0xFFFF0000u);
                    a8[2*i]   += w01 * __builtin_bit_cast(float, u01[i] << 16);
                    a8[2*i+1] += w01 * __builtin_bit_cast(float, u01[i] & 0xFFFF0000u);
                    a8[2*i]   += w10 * __builtin_bit_cast(float, u10[i] << 16);
                    a8[2*i+1] += w10 * __builtin_bit_cast(float, u10[i] & 0xFFFF0000u);
                    a8[2*i]   += w11 * __builtin_bit_cast(float, u11[i] << 16);
                    a8[2*i+1] += w11 * __builtin_bit_cast(float, u11[i] & 0xFFFF0000u);
                }
                uint4 ov;
                ov.x = cvt_pk_bf16(a8[0], a8[1]);
                ov.y = cvt_pk_bf16(a8[2], a8[3]);
                ov.z = cvt_pk_bf16(a8[4], a8[5]);
                ov.w = cvt_pk_bf16(a8[6], a8[7]);
                int slot = t ^ (pix & 7);
                *(uint4*)(lds + pix * 256 + slot * 16) = ov;
            }
        }
        __syncthreads();
        #pragma unroll
        for (int ck = 0; ck < 3; ++ck) {
            short8 bfr = ((const short8*)Btd)[((size_t)(g * 3 + ck) * 4 + wv) * 64 + lane];
            const int slotbase = ck * 4 + l16;
            #pragma unroll
            for (int mf = 0; mf < 4; ++mf) {
                int row = mf * 16 + lm;
                int slot = slotbase ^ (lm & 7);
                short8 afr = *(const short8*)(lds + row * 256 + slot * 16);
                acc[mf] = __builtin_amdgcn_mfma_f32_16x16x32_bf16(
                    afr, bfr, acc[mf], 0, 0, 0);
            }
        }
    }

    const int oc = wv * 16 + lm;
    #pragma unroll
    for (int mf = 0; mf < 4; ++mf) {
        int px = hw0 + mf * 16 + l16 * 4;
        *(f32x4*)(out + (size_t)(b * 64 + oc) * HW_ + px) = acc[mf];
    }
}

// ---------------------------------------------------------------------------
extern "C" void kernel_launch(void* const* d_in, const int* in_sizes, int n_in,
                              void* d_out, int out_size, void* d_ws, size_t ws_size,
                              hipStream_t stream)
{
    const float* cfw  = (const float*)d_in[0];
    const float* fpro = (const float*)d_in[1];
    const float* fprv = (const float*)d_in[2];
    const float* fl1  = (const float*)d_in[3];
    const float* fl2  = (const float*)d_in[4];
    const float* w1   = (const float*)d_in[5];
    const float* b1   = (const float*)d_in[6];
    const float* w2   = (const float*)d_in[7];
    const float* b2   = (const float*)d_in[8];
    const float* w3   = (const float*)d_in[9];
    const float* b3   = (const float*)d_in[10];
    const float* w4   = (const float*)d_in[11];
    const float* b4   = (const float*)d_in[12];
    const float* wdef = (const float*)d_in[13];
    const float* bdef = (const float*)d_in[14];
    float* out = (float*)d_out;

    // ---- workspace layout (bytes) ----
    char* ws = (char*)d_ws;
    unsigned short* X1  = (unsigned short*)(ws);
    unsigned short* buf1= (unsigned short*)(ws + 55050240);   // o1 / o3
    unsigned short* o2  = (unsigned short*)(ws + 70778880);   // dead after conv3
    unsigned short* oY  = (unsigned short*)(ws + 70778880);   // clobbers o2 (OK)
    unsigned short* oX  = oY + (size_t)72 * NPIX;
    unsigned short* oM  = oX + (size_t)72 * NPIX;
    unsigned short* Bt1 = (unsigned short*)(ws + 125829120);
    unsigned short* Bt2 = (unsigned short*)(ws + 125829120 + 258048);
    unsigned short* Bt3 = (unsigned short*)(ws + 125829120 + 258048 + 73728);
    unsigned short* Bt4 = (unsigned short*)(ws + 125829120 + 258048 + 2*73728);
    unsigned short* Btd = (unsigned short*)(ws + 125829120 + 2*258048 + 2*73728);

    prep_x1<<<dim3(NPIX / 1024, 28), dim3(256), 0, stream>>>(
        cfw, fpro, fprv, fl1, fl2, X1);
    prep_wall<<<dim3((47616 + 255) / 256), dim3(256), 0, stream>>>(
        w1, w2, w3, w4, wdef, Bt1, Bt2, Bt3, Bt4, Btd);

    dim3 blk(256);
    dim3 gridM(NPIX / 128, 1);
    // conv1: X1(196) -> o1 (buf1), lrelu
    conv_mfma<7, 4, 4, true><<<gridM, blk, 0, stream>>>(X1, Bt1, b1, buf1, 64, 0);
    // conv2: o1 (buf1) -> o2, lrelu
    conv_mfma<2, 4, 4, true><<<gridM, blk, 0, stream>>>(buf1, Bt2, b2, o2, 64, 0);
    // conv3: o2 -> o3 (buf1, o1 dead), lrelu
    conv_mfma<2, 4, 4, true><<<gridM, blk, 0, stream>>>(o2, Bt3, b3, buf1, 64, 0);
    // conv4: o3 (buf1) -> channel-planar oY/oX/oM, ONE dispatch (y = half)
    conv4_mfma<<<dim3(NPIX / 128, 2), blk, 0, stream>>>(buf1, Bt4, b4, oY, oX, oM);
    // fused deformable conv: 64-px blocks, 256 threads, 16-oc-slice waves
    deform_mfma<<<dim3(NPIX / 64), blk, 0, stream>>>(
        X1, oY, oX, oM, fl1, fl2, Btd, bdef, out);
}

// Round 19
// 241.448 us; speedup vs baseline: 1.0258x; 1.0020x over previous
//
#include <hip/hip_runtime.h>
#include <hip/hip_bf16.h>
#include <math.h>

typedef __attribute__((ext_vector_type(8))) short short8;
typedef __attribute__((ext_vector_type(4))) float f32x4;

constexpr int B_ = 8, H_ = 96, W_ = 160;
constexpr int HW_ = H_ * W_;
constexpr int NPIX = B_ * HW_;        // 122880

__device__ __forceinline__ unsigned short f2bf(float f) {
    unsigned int u = __builtin_bit_cast(unsigned int, f);
    u += 0x7FFFu + ((u >> 16) & 1u);          // RNE
    return (unsigned short)(u >> 16);
}
__device__ __forceinline__ float bf2f(unsigned short s) {
    unsigned int u = ((unsigned int)s) << 16;
    return __builtin_bit_cast(float, u);
}
__device__ __forceinline__ unsigned int cvt_pk_bf16(float lo, float hi) {
    unsigned int r;
    asm volatile("v_cvt_pk_bf16_f32 %0, %1, %2" : "=v"(r) : "v"(lo), "v"(hi));
    return r;   // D[15:0]=bf16(lo), D[31:16]=bf16(hi)
}
__device__ __forceinline__ float f4get(const float4& v, int q) {
    switch (q) { case 0: return v.x; case 1: return v.y;
                 case 2: return v.z; default: return v.w; }
}
// XCD-bijective swizzle for 960-block conv grids (960 = 8*120)
__device__ __forceinline__ int swz960(int bid) {
    return (bid & 7) * 120 + (bid >> 3);
}

// ---------------------------------------------------------------------------
// Prep 1: concat inputs -> octet-planar bf16 X1[c8][NPIX][8], c8 = 0..27.
// ---------------------------------------------------------------------------
__global__ __launch_bounds__(256) void prep_x1(
    const float* __restrict__ cfw, const float* __restrict__ fpro,
    const float* __restrict__ fprv, const float* __restrict__ f1,
    const float* __restrict__ f2, unsigned short* __restrict__ X1)
{
    const int c8 = blockIdx.y;
    const int pix0 = blockIdx.x * 1024 + threadIdx.x * 4;   // grid.x = NPIX/1024
    unsigned short* dst = X1 + ((size_t)c8 * NPIX + pix0) * 8;

    if (c8 >= 25) {   // channels 200..223 are all zero
        uint4 z = {0u, 0u, 0u, 0u};
        #pragma unroll
        for (int q = 0; q < 4; ++q) *(uint4*)(dst + q * 8) = z;
        return;
    }

    const int b  = pix0 / HW_;          // 1024 | HW_, no batch crossing
    const int hw = pix0 - b * HW_;

    float4 v[8];
    #pragma unroll
    for (int j = 0; j < 8; ++j) {
        int c = c8 * 8 + j;
        const float* src = nullptr; int sc = 0, nc = 0;
        if (c < 64)       { src = cfw;  sc = c;       nc = 64; }
        else if (c < 128) { src = fpro; sc = c - 64;  nc = 64; }
        else if (c < 192) { src = fprv; sc = c - 128; nc = 64; }
        else if (c < 194) { src = f1;   sc = c - 192; nc = 2;  }
        else if (c < 196) { src = f2;   sc = c - 194; nc = 2;  }
        if (src) v[j] = *(const float4*)(src + ((size_t)b * nc + sc) * HW_ + hw);
        else     { v[j].x = v[j].y = v[j].z = v[j].w = 0.f; }
    }
    #pragma unroll
    for (int q = 0; q < 4; ++q) {
        uint4 o;
        o.x = cvt_pk_bf16(f4get(v[0], q), f4get(v[1], q));
        o.y = cvt_pk_bf16(f4get(v[2], q), f4get(v[3], q));
        o.z = cvt_pk_bf16(f4get(v[4], q), f4get(v[5], q));
        o.w = cvt_pk_bf16(f4get(v[6], q), f4get(v[7], q));
        *(uint4*)(dst + q * 8) = o;
    }
}

// ---------------------------------------------------------------------------
// Prep 2 (merged): ALL weight packs in ONE dispatch.
// ---------------------------------------------------------------------------
__device__ __forceinline__ void pack_conv_w(
    const float* __restrict__ w, unsigned short* __restrict__ Bt, int idx,
    int Cin, int KCH, int Nout, int NFTOT)
{
    int lane = idx & 63;
    int r = idx >> 6;
    int nf = r % NFTOT; r /= NFTOT;
    int ck = r % KCH;
    int t  = r / KCH;
    int n  = nf * 16 + (lane & 15);
    int kb = ck * 32 + (lane >> 4) * 8;
    short8 o;
    #pragma unroll
    for (int j = 0; j < 8; ++j) {
        int c = kb + j;
        float v = (c < Cin && n < Nout) ? w[((size_t)n * Cin + c) * 9 + t] : 0.f;
        o[j] = (short)f2bf(v);
    }
    *(short8*)(Bt + (size_t)idx * 8) = o;
}

__global__ __launch_bounds__(256) void prep_wall(
    const float* __restrict__ w1, const float* __restrict__ w2,
    const float* __restrict__ w3, const float* __restrict__ w4,
    const float* __restrict__ wd,
    unsigned short* __restrict__ Bt1, unsigned short* __restrict__ Bt2,
    unsigned short* __restrict__ Bt3, unsigned short* __restrict__ Bt4,
    unsigned short* __restrict__ Btd)
{
    int idx = blockIdx.x * 256 + threadIdx.x;
    if (idx < 16128)      pack_conv_w(w1, Bt1, idx,          196, 7,  64,  4);
    else if (idx < 20736) pack_conv_w(w2, Bt2, idx - 16128,   64, 2,  64,  4);
    else if (idx < 25344) pack_conv_w(w3, Bt3, idx - 20736,   64, 2,  64,  4);
    else if (idx < 41472) pack_conv_w(w4, Bt4, idx - 25344,   64, 2, 216, 14);
    else if (idx < 47616) {
        int id2 = idx - 41472;
        int lane = id2 & 63;
        int r = id2 >> 6;
        int nf = r % 4; r >>= 2;
        int ck = r % 3;
        int g  = r / 3;
        int n  = nf * 16 + (lane & 15);             // oc
        int kb = ck * 32 + (lane >> 4) * 8;
        short8 o;
        #pragma unroll
        for (int j = 0; j < 8; ++j) {
            int k = kb + j;
            int t = k >> 3, c = k & 7;
            float v = (t < 9) ? wd[((size_t)n * 64 + g * 8 + c) * 9 + t] : 0.f;
            o[j] = (short)f2bf(v);
        }
        *(short8*)(Btd + (size_t)id2 * 8) = o;
    }
}

// ---------------------------------------------------------------------------
// MFMA implicit-GEMM 3x3 conv, pad=1 (128-px blocks, wave = 32 px, triplet
// B-staging with 3 named prefetch regs) + XCD swizzle. (round-16 known good)
// ---------------------------------------------------------------------------
template<int KCH, int NFTOT, int NF, bool RELU>
__global__ __launch_bounds__(256) void conv_mfma(
    const unsigned short* __restrict__ X, const unsigned short* __restrict__ Bt,
    const float* __restrict__ bias, unsigned short* __restrict__ Y,
    int CoutTot, int fBase0)
{
    static_assert(NF == 4, "staging assumes 4 KB per tap chunk");
    __shared__ __align__(16) unsigned short bsh[3 * 2048];   // 12 KB

    const int tid  = threadIdx.x;
    const int lane = tid & 63;
    const int wv   = tid >> 6;
    const int m0   = swz960(blockIdx.x) * 128 + wv * 32;
    const int fBase = fBase0 + blockIdx.y * NF;
    const int lm = lane & 15;
    const int l16 = lane >> 4;

    int p[2], hh[2], wp[2];
    #pragma unroll
    for (int mf = 0; mf < 2; ++mf) {
        int pm = m0 + mf * 16 + lm;
        p[mf] = pm;
        hh[mf] = (pm / W_) % H_;
        wp[mf] = pm % W_;
    }

    f32x4 acc[2][NF];
    #pragma unroll
    for (int nf = 0; nf < NF; ++nf) {
        int oc = (fBase + nf) * 16 + lm;
        float bv = (oc < CoutTot) ? bias[oc] : 0.f;
        f32x4 a = {bv, bv, bv, bv};
        acc[0][nf] = a; acc[1][nf] = a;
    }

    const short8 zero = {0,0,0,0,0,0,0,0};
    constexpr int S3 = KCH * 3;          // triplet count

    uint4 bta = *(const uint4*)(Bt + ((size_t)(0 * KCH) * NFTOT + fBase) * 512 + tid * 8);
    uint4 btb = *(const uint4*)(Bt + ((size_t)(1 * KCH) * NFTOT + fBase) * 512 + tid * 8);
    uint4 btc = *(const uint4*)(Bt + ((size_t)(2 * KCH) * NFTOT + fBase) * 512 + tid * 8);

    for (int s3 = 0; s3 < S3; ++s3) {
        const int ck = s3 / 3, tb = (s3 % 3) * 3;
        __syncthreads();
        *(uint4*)(bsh + 0 * 2048 + tid * 8) = bta;
        *(uint4*)(bsh + 1 * 2048 + tid * 8) = btb;
        *(uint4*)(bsh + 2 * 2048 + tid * 8) = btc;
        __syncthreads();
        if (s3 + 1 < S3) {
            const int ck2 = (s3 + 1) / 3, tb2 = ((s3 + 1) % 3) * 3;
            bta = *(const uint4*)(Bt + ((size_t)((tb2 + 0) * KCH + ck2) * NFTOT + fBase) * 512 + tid * 8);
            btb = *(const uint4*)(Bt + ((size_t)((tb2 + 1) * KCH + ck2) * NFTOT + fBase) * 512 + tid * 8);
            btc = *(const uint4*)(Bt + ((size_t)((tb2 + 2) * KCH + ck2) * NFTOT + fBase) * 512 + tid * 8);
        }
        const unsigned short* Xp = X + (size_t)(ck * 4 + l16) * NPIX * 8;
        #pragma unroll
        for (int j = 0; j < 3; ++j) {
            const int t = tb + j;
            const int di = t / 3 - 1, dj = t % 3 - 1;
            short8 bfr[NF];
            #pragma unroll
            for (int nf = 0; nf < NF; ++nf)
                bfr[nf] = *(const short8*)(bsh + j * 2048 + nf * 512 + lane * 8);
            #pragma unroll
            for (int mf = 0; mf < 2; ++mf) {
                bool val = ((unsigned)(hh[mf] + di) < (unsigned)H_) &&
                           ((unsigned)(wp[mf] + dj) < (unsigned)W_);
                const unsigned short* ap = Xp + (size_t)(p[mf] + di * W_ + dj) * 8;
                short8 afr = val ? *(const short8*)ap : zero;
                #pragma unroll
                for (int nf = 0; nf < NF; ++nf)
                    acc[mf][nf] = __builtin_amdgcn_mfma_f32_16x16x32_bf16(
                        afr, bfr[nf], acc[mf][nf], 0, 0, 0);
            }
        }
    }

    const int prow = l16 * 4;
    #pragma unroll
    for (int mf = 0; mf < 2; ++mf)
        #pragma unroll
        for (int nf = 0; nf < NF; ++nf) {
            int oc = (fBase + nf) * 16 + lm;
            if (oc < CoutTot) {
                #pragma unroll
                for (int r = 0; r < 4; ++r) {
                    int pix = m0 + mf * 16 + prow + r;
                    float v = acc[mf][nf][r];
                    if (RELU) v = (v >= 0.f) ? v : 0.1f * v;
                    Y[((size_t)(oc >> 3) * NPIX + pix) * 8 + (oc & 7)] = f2bf(v);
                }
            }
        }
}

// ---------------------------------------------------------------------------
// conv4: ONE dispatch, grid (960, 2); FB = blockIdx.y*7. + XCD swizzle.
// (round-16 known good)
// ---------------------------------------------------------------------------
__global__ __launch_bounds__(256, 4) void conv4_mfma(
    const unsigned short* __restrict__ X, const unsigned short* __restrict__ Bt,
    const float* __restrict__ bias,
    unsigned short* __restrict__ oY, unsigned short* __restrict__ oX,
    unsigned short* __restrict__ oM)
{
    __shared__ __align__(16) unsigned short bsh[7 * 512];   // 7168 B

    const int tid  = threadIdx.x;
    const int lane = tid & 63;
    const int wv   = tid >> 6;
    const int pix0 = swz960(blockIdx.x) * 128;
    const int m0   = pix0 + wv * 32;
    const int lm = lane & 15;
    const int l16 = lane >> 4;
    const int FB = blockIdx.y * 7;         // frag base (block-uniform)

    int p[2], hh[2], wp[2];
    #pragma unroll
    for (int mf = 0; mf < 2; ++mf) {
        int pm = m0 + mf * 16 + lm;
        p[mf] = pm;
        hh[mf] = (pm / W_) % H_;
        wp[mf] = pm % W_;
    }

    f32x4 acc[2][7];
    #pragma unroll
    for (int nf = 0; nf < 7; ++nf) {
        int oc = (FB + nf) * 16 + lm;
        float bv = (oc < 216) ? bias[oc] : 0.f;
        f32x4 a = {bv, bv, bv, bv};
        acc[0][nf] = a; acc[1][nf] = a;
    }

    const short8 zero = {0,0,0,0,0,0,0,0};
    const bool two = (tid < 192);

    uint4 bt0 = *(const uint4*)(Bt + (size_t)FB * 512 + tid * 8);
    uint4 bt1 = {0u, 0u, 0u, 0u};
    if (two) bt1 = *(const uint4*)(Bt + (size_t)FB * 512 + (256 + tid) * 8);

    #pragma unroll
    for (int s = 0; s < 18; ++s) {
        const int ck = s / 9, t = s % 9;
        __syncthreads();
        *(uint4*)(bsh + tid * 8) = bt0;
        if (two) *(uint4*)(bsh + (256 + tid) * 8) = bt1;
        __syncthreads();
        if (s + 1 < 18) {
            const int ck2 = (s + 1) / 9, t2 = (s + 1) % 9;
            const unsigned short* nb =
                Bt + ((size_t)((t2 * 2 + ck2) * 14 + FB)) * 512;
            bt0 = *(const uint4*)(nb + tid * 8);
            if (two) bt1 = *(const uint4*)(nb + (256 + tid) * 8);
        }
        const int di = t / 3 - 1, dj = t % 3 - 1;
        const unsigned short* Xp = X + (size_t)(ck * 4 + l16) * NPIX * 8;
        short8 afr[2];
        #pragma unroll
        for (int mf = 0; mf < 2; ++mf) {
            bool val = ((unsigned)(hh[mf] + di) < (unsigned)H_) &&
                       ((unsigned)(wp[mf] + dj) < (unsigned)W_);
            const unsigned short* ap = Xp + (size_t)(p[mf] + di * W_ + dj) * 8;
            afr[mf] = val ? *(const short8*)ap : zero;
        }
        #pragma unroll
        for (int nf = 0; nf < 7; ++nf) {
            short8 bfr = *(const short8*)(bsh + nf * 512 + lane * 8);
            acc[0][nf] = __builtin_amdgcn_mfma_f32_16x16x32_bf16(
                afr[0], bfr, acc[0][nf], 0, 0, 0);
            acc[1][nf] = __builtin_amdgcn_mfma_f32_16x16x32_bf16(
                afr[1], bfr, acc[1][nf], 0, 0, 0);
        }
    }

    const int prow = l16 * 4;
    #pragma unroll
    for (int mf = 0; mf < 2; ++mf) {
        const int pixb = m0 + mf * 16 + prow;      // 4 consecutive pixels
        #pragma unroll
        for (int nf = 0; nf < 7; ++nf) {
            const int nfg = FB + nf;               // block-uniform
            const int oc = nfg * 16 + lm;
            if (nfg < 9) {
                const int pr = nfg * 8 + (lm >> 1);
                unsigned short* plane = ((lm & 1) ? oX : oY) + (size_t)pr * NPIX;
                uint2 sv;
                sv.x = cvt_pk_bf16(acc[mf][nf][0], acc[mf][nf][1]);
                sv.y = cvt_pk_bf16(acc[mf][nf][2], acc[mf][nf][3]);
                *(uint2*)(plane + pixb) = sv;
            } else if (oc < 216) {
                const int mi = (nfg - 9) * 16 + lm;
                float v0 = 1.f / (1.f + expf(-acc[mf][nf][0]));
                float v1 = 1.f / (1.f + expf(-acc[mf][nf][1]));
                float v2 = 1.f / (1.f + expf(-acc[mf][nf][2]));
                float v3 = 1.f / (1.f + expf(-acc[mf][nf][3]));
                uint2 sv;
                sv.x = cvt_pk_bf16(v0, v1);
                sv.y = cvt_pk_bf16(v2, v3);
                *(uint2*)(oM + (size_t)mi * NPIX + pixb) = sv;
            }
        }
    }
}

// ---------------------------------------------------------------------------
// Fused deformable conv — v19: DOUBLE-BUFFERED LDS (2 x 16 KB). Sample group
// g+1 into buffer B while MFMA for group g reads buffer A; ONE barrier per
// group (10 total vs 16). Gather latency of g+1 hides under g's MFMA within
// the same phase. No new register state (buffer select = LDS addr math).
// ---------------------------------------------------------------------------
__global__ __launch_bounds__(256) void deform_mfma(
    const unsigned short* __restrict__ Xg,   // [8][NPIX][8] bf16 planes (X1)
    const unsigned short* __restrict__ oY,   // [72][NPIX] bf16 raw dy
    const unsigned short* __restrict__ oX,   // [72][NPIX] bf16 raw dx
    const unsigned short* __restrict__ oM,   // [72][NPIX] bf16 sigmoid(mask)
    const float* __restrict__ f1, const float* __restrict__ f2,
    const unsigned short* __restrict__ Btd,  // [8][3][4][64][8] bf16
    const float* __restrict__ bia,           // 64
    float* __restrict__ out)                 // B,64,H,W fp32 NCHW
{
    __shared__ __align__(16) char lds[2 * 16384];   // 32 KB, two buffers

    const int tid  = threadIdx.x;             // 0..255
    const int lane = tid & 63;
    const int wv   = tid >> 6;                // 0..3
    const int lm   = lane & 15;
    const int l16  = lane >> 4;
    const int pix0 = blockIdx.x * 64;
    const int b    = pix0 / HW_;
    const int hw0  = pix0 % HW_;

    const int pix = tid & 63;
    const int hw  = hw0 + pix;
    const int h   = hw / W_;
    const int w   = hw - h * W_;
    const size_t gp = (size_t)(pix0 + pix);
    const size_t bF = (size_t)b * 2 * HW_;

    // zero BOTH buffers (slots never written by sampling stay zero; written
    // slots are fully overwritten each reuse)
    {
        uint4 z = {0u, 0u, 0u, 0u};
        #pragma unroll
        for (int i = 0; i < 8; ++i)
            ((uint4*)lds)[i * 256 + tid] = z;
    }

    f32x4 acc[4];            // wave's 16-oc slice (oc = wv*16+lm), 64 px
    {
        float bv = bia[wv * 16 + lm];
        f32x4 a = {bv, bv, bv, bv};
        #pragma unroll
        for (int mf = 0; mf < 4; ++mf) acc[mf] = a;
    }

    // sampling for group g into buffer buf (3 taps/thread, t = wv + 4*it)
    auto sample = [&](int g, char* buf) {
        const unsigned short* Xp = Xg + (size_t)g * NPIX * 8;
        const float* fl = (g < 4) ? f1 : f2;
        const float fy = fl[bF + (size_t)HW_ + hw];
        const float fx = fl[bF + hw];
        unsigned short uy[3], ux[3], um[3];
        #pragma unroll
        for (int it = 0; it < 3; ++it) {
            int t = wv + 4 * it;
            bool act = (it < 2) || (wv == 0);
            if (act) {
                size_t po = (size_t)(g * 9 + t) * NPIX + gp;
                uy[it] = oY[po]; ux[it] = oX[po]; um[it] = oM[po];
            }
        }
        #pragma unroll
        for (int it = 0; it < 3; ++it) {
            int t = wv + 4 * it;
            bool act = (it < 2) || (wv == 0);
            if (act) {
                float dy = bf2f(uy[it]) + fy;
                float dx = bf2f(ux[it]) + fx;
                float m  = bf2f(um[it]);

                float ys = dy + (float)(h - 1 + t / 3);
                float xs = dx + (float)(w - 1 + t % 3);
                float y0f = floorf(ys), x0f = floorf(xs);
                float wy1 = ys - y0f, wx1 = xs - x0f;
                float wy0 = 1.f - wy1, wx0 = 1.f - wx1;
                int iy0 = (int)y0f, ix0 = (int)x0f;
                int iy1 = iy0 + 1,  ix1 = ix0 + 1;
                bool vy0 = (unsigned)iy0 < (unsigned)H_;
                bool vy1 = (unsigned)iy1 < (unsigned)H_;
                bool vx0 = (unsigned)ix0 < (unsigned)W_;
                bool vx1 = (unsigned)ix1 < (unsigned)W_;
                int cy0 = min(max(iy0, 0), H_ - 1), cy1 = min(max(iy1, 0), H_ - 1);
                int cx0 = min(max(ix0, 0), W_ - 1), cx1 = min(max(ix1, 0), W_ - 1);
                float w00 = (vy0 && vx0) ? wy0 * wx0 * m : 0.f;
                float w01 = (vy0 && vx1) ? wy0 * wx1 * m : 0.f;
                float w10 = (vy1 && vx0) ? wy1 * wx0 * m : 0.f;
                float w11 = (vy1 && vx1) ? wy1 * wx1 * m : 0.f;

                size_t r0 = (size_t)b * HW_ + (size_t)cy0 * W_;
                size_t r1 = (size_t)b * HW_ + (size_t)cy1 * W_;
                uint4 c00 = *(const uint4*)(Xp + (r0 + cx0) * 8);
                uint4 c01 = *(const uint4*)(Xp + (r0 + cx1) * 8);
                uint4 c10 = *(const uint4*)(Xp + (r1 + cx0) * 8);
                uint4 c11 = *(const uint4*)(Xp + (r1 + cx1) * 8);

                float a8[8];
                #pragma unroll
                for (int i = 0; i < 8; ++i) a8[i] = 0.f;
                const unsigned int u00[4] = {c00.x, c00.y, c00.z, c00.w};
                const unsigned int u01[4] = {c01.x, c01.y, c01.z, c01.w};
                const unsigned int u10[4] = {c10.x, c10.y, c10.z, c10.w};
                const unsigned int u11[4] = {c11.x, c11.y, c11.z, c11.w};
                #pragma unroll
                for (int i = 0; i < 4; ++i) {
                    a8[2*i]   += w00 * __builtin_bit_cast(float, u00[i] << 16);
                    a8[2*i+1] += w00 * __builtin_bit_cast(float, u00[i] & 0xFFFF0000u);
                    a8[2*i]   += w01 * __builtin_bit_cast(float, u01[i] << 16);
                    a8[2*i+1] += w01 * __builtin_bit_cast(float, u01[i] & 0xFFFF0000u);
                    a8[2*i]   += w10 * __builtin_bit_cast(float, u10[i] << 16);
                    a8[2*i+1] += w10 * __builtin_bit_cast(float, u10[i] & 0xFFFF0000u);
                    a8[2*i]   += w11 * __builtin_bit_cast(float, u11[i] << 16);
                    a8[2*i+1] += w11 * __builtin_bit_cast(float, u11[i] & 0xFFFF0000u);
                }
                uint4 ov;
                ov.x = cvt_pk_bf16(a8[0], a8[1]);
                ov.y = cvt_pk_bf16(a8[2], a8[3]);
                ov.z = cvt_pk_bf16(a8[4], a8[5]);
                ov.w = cvt_pk_bf16(a8[6], a8[7]);
                int slot = t ^ (pix & 7);
                *(uint4*)(buf + pix * 256 + slot * 16) = ov;
            }
        }
    };

    __syncthreads();          // zero-init visible
    sample(0, lds);           // prologue: group 0 -> buffer 0
    __syncthreads();          // buffer 0 ready

    for (int g = 0; g < 8; ++g) {
        char* cur = lds + (g & 1) * 16384;
        char* nxt = lds + ((g + 1) & 1) * 16384;
        // issue next group's sampling first (overlaps with MFMA below)
        if (g < 7) sample(g + 1, nxt);
        // MFMA for current group from cur
        #pragma unroll
        for (int ck = 0; ck < 3; ++ck) {
            short8 bfr = ((const short8*)Btd)[((size_t)(g * 3 + ck) * 4 + wv) * 64 + lane];
            const int slotbase = ck * 4 + l16;
            #pragma unroll
            for (int mf = 0; mf < 4; ++mf) {
                int row = mf * 16 + lm;
                int slot = slotbase ^ (lm & 7);
                short8 afr = *(const short8*)(cur + row * 256 + slot * 16);
                acc[mf] = __builtin_amdgcn_mfma_f32_16x16x32_bf16(
                    afr, bfr, acc[mf], 0, 0, 0);
            }
        }
        __syncthreads();      // cur reads done (next iter writes cur);
                              // nxt writes visible for next iter's MFMA
    }

    const int oc = wv * 16 + lm;
    #pragma unroll
    for (int mf = 0; mf < 4; ++mf) {
        int px = hw0 + mf * 16 + l16 * 4;
        *(f32x4*)(out + (size_t)(b * 64 + oc) * HW_ + px) = acc[mf];
    }
}

// ---------------------------------------------------------------------------
extern "C" void kernel_launch(void* const* d_in, const int* in_sizes, int n_in,
                              void* d_out, int out_size, void* d_ws, size_t ws_size,
                              hipStream_t stream)
{
    const float* cfw  = (const float*)d_in[0];
    const float* fpro = (const float*)d_in[1];
    const float* fprv = (const float*)d_in[2];
    const float* fl1  = (const float*)d_in[3];
    const float* fl2  = (const float*)d_in[4];
    const float* w1   = (const float*)d_in[5];
    const float* b1   = (const float*)d_in[6];
    const float* w2   = (const float*)d_in[7];
    const float* b2   = (const float*)d_in[8];
    const float* w3   = (const float*)d_in[9];
    const float* b3   = (const float*)d_in[10];
    const float* w4   = (const float*)d_in[11];
    const float* b4   = (const float*)d_in[12];
    const float* wdef = (const float*)d_in[13];
    const float* bdef = (const float*)d_in[14];
    float* out = (float*)d_out;

    // ---- workspace layout (bytes) ----
    char* ws = (char*)d_ws;
    unsigned short* X1  = (unsigned short*)(ws);
    unsigned short* buf1= (unsigned short*)(ws + 55050240);   // o1 / o3
    unsigned short* o2  = (unsigned short*)(ws + 70778880);   // dead after conv3
    unsigned short* oY  = (unsigned short*)(ws + 70778880);   // clobbers o2 (OK)
    unsigned short* oX  = oY + (size_t)72 * NPIX;
    unsigned short* oM  = oX + (size_t)72 * NPIX;
    unsigned short* Bt1 = (unsigned short*)(ws + 125829120);
    unsigned short* Bt2 = (unsigned short*)(ws + 125829120 + 258048);
    unsigned short* Bt3 = (unsigned short*)(ws + 125829120 + 258048 + 73728);
    unsigned short* Bt4 = (unsigned short*)(ws + 125829120 + 258048 + 2*73728);
    unsigned short* Btd = (unsigned short*)(ws + 125829120 + 2*258048 + 2*73728);

    prep_x1<<<dim3(NPIX / 1024, 28), dim3(256), 0, stream>>>(
        cfw, fpro, fprv, fl1, fl2, X1);
    prep_wall<<<dim3((47616 + 255) / 256), dim3(256), 0, stream>>>(
        w1, w2, w3, w4, wdef, Bt1, Bt2, Bt3, Bt4, Btd);

    dim3 blk(256);
    dim3 gridM(NPIX / 128, 1);
    // conv1: X1(196) -> o1 (buf1), lrelu
    conv_mfma<7, 4, 4, true><<<gridM, blk, 0, stream>>>(X1, Bt1, b1, buf1, 64, 0);
    // conv2: o1 (buf1) -> o2, lrelu
    conv_mfma<2, 4, 4, true><<<gridM, blk, 0, stream>>>(buf1, Bt2, b2, o2, 64, 0);
    // conv3: o2 -> o3 (buf1, o1 dead), lrelu
    conv_mfma<2, 4, 4, true><<<gridM, blk, 0, stream>>>(o2, Bt3, b3, buf1, 64, 0);
    // conv4: o3 (buf1) -> channel-planar oY/oX/oM, ONE dispatch (y = half)
    conv4_mfma<<<dim3(NPIX / 128, 2), blk, 0, stream>>>(buf1, Bt4, b4, oY, oX, oM);
    // fused deformable conv: double-buffered LDS, one barrier per group
    deform_mfma<<<dim3(NPIX / 64), blk, 0, stream>>>(
        X1, oY, oX, oM, fl1, fl2, Btd, bdef, out);
}

// Round 20
// 239.817 us; speedup vs baseline: 1.0328x; 1.0068x over previous
//
#include <hip/hip_runtime.h>
#include <hip/hip_bf16.h>
#include <math.h>

typedef __attribute__((ext_vector_type(8))) short short8;
typedef __attribute__((ext_vector_type(4))) float f32x4;

constexpr int B_ = 8, H_ = 96, W_ = 160;
constexpr int HW_ = H_ * W_;
constexpr int NPIX = B_ * HW_;        // 122880

__device__ __forceinline__ unsigned short f2bf(float f) {
    unsigned int u = __builtin_bit_cast(unsigned int, f);
    u += 0x7FFFu + ((u >> 16) & 1u);          // RNE
    return (unsigned short)(u >> 16);
}
__device__ __forceinline__ float bf2f(unsigned short s) {
    unsigned int u = ((unsigned int)s) << 16;
    return __builtin_bit_cast(float, u);
}
__device__ __forceinline__ unsigned int cvt_pk_bf16(float lo, float hi) {
    unsigned int r;
    asm volatile("v_cvt_pk_bf16_f32 %0, %1, %2" : "=v"(r) : "v"(lo), "v"(hi));
    return r;   // D[15:0]=bf16(lo), D[31:16]=bf16(hi)
}
__device__ __forceinline__ float f4get(const float4& v, int q) {
    switch (q) { case 0: return v.x; case 1: return v.y;
                 case 2: return v.z; default: return v.w; }
}
// XCD-bijective swizzle for 960-block conv grids (960 = 8*120)
__device__ __forceinline__ int swz960(int bid) {
    return (bid & 7) * 120 + (bid >> 3);
}

// ---------------------------------------------------------------------------
// Prep 1: concat inputs -> octet-planar bf16 X1[c8][NPIX][8], c8 = 0..27.
// ---------------------------------------------------------------------------
__global__ __launch_bounds__(256) void prep_x1(
    const float* __restrict__ cfw, const float* __restrict__ fpro,
    const float* __restrict__ fprv, const float* __restrict__ f1,
    const float* __restrict__ f2, unsigned short* __restrict__ X1)
{
    const int c8 = blockIdx.y;
    const int pix0 = blockIdx.x * 1024 + threadIdx.x * 4;   // grid.x = NPIX/1024
    unsigned short* dst = X1 + ((size_t)c8 * NPIX + pix0) * 8;

    if (c8 >= 25) {   // channels 200..223 are all zero
        uint4 z = {0u, 0u, 0u, 0u};
        #pragma unroll
        for (int q = 0; q < 4; ++q) *(uint4*)(dst + q * 8) = z;
        return;
    }

    const int b  = pix0 / HW_;          // 1024 | HW_, no batch crossing
    const int hw = pix0 - b * HW_;

    float4 v[8];
    #pragma unroll
    for (int j = 0; j < 8; ++j) {
        int c = c8 * 8 + j;
        const float* src = nullptr; int sc = 0, nc = 0;
        if (c < 64)       { src = cfw;  sc = c;       nc = 64; }
        else if (c < 128) { src = fpro; sc = c - 64;  nc = 64; }
        else if (c < 192) { src = fprv; sc = c - 128; nc = 64; }
        else if (c < 194) { src = f1;   sc = c - 192; nc = 2;  }
        else if (c < 196) { src = f2;   sc = c - 194; nc = 2;  }
        if (src) v[j] = *(const float4*)(src + ((size_t)b * nc + sc) * HW_ + hw);
        else     { v[j].x = v[j].y = v[j].z = v[j].w = 0.f; }
    }
    #pragma unroll
    for (int q = 0; q < 4; ++q) {
        uint4 o;
        o.x = cvt_pk_bf16(f4get(v[0], q), f4get(v[1], q));
        o.y = cvt_pk_bf16(f4get(v[2], q), f4get(v[3], q));
        o.z = cvt_pk_bf16(f4get(v[4], q), f4get(v[5], q));
        o.w = cvt_pk_bf16(f4get(v[6], q), f4get(v[7], q));
        *(uint4*)(dst + q * 8) = o;
    }
}

// ---------------------------------------------------------------------------
// Prep 2 (merged): ALL weight packs in ONE dispatch.
// ---------------------------------------------------------------------------
__device__ __forceinline__ void pack_conv_w(
    const float* __restrict__ w, unsigned short* __restrict__ Bt, int idx,
    int Cin, int KCH, int Nout, int NFTOT)
{
    int lane = idx & 63;
    int r = idx >> 6;
    int nf = r % NFTOT; r /= NFTOT;
    int ck = r % KCH;
    int t  = r / KCH;
    int n  = nf * 16 + (lane & 15);
    int kb = ck * 32 + (lane >> 4) * 8;
    short8 o;
    #pragma unroll
    for (int j = 0; j < 8; ++j) {
        int c = kb + j;
        float v = (c < Cin && n < Nout) ? w[((size_t)n * Cin + c) * 9 + t] : 0.f;
        o[j] = (short)f2bf(v);
    }
    *(short8*)(Bt + (size_t)idx * 8) = o;
}

__global__ __launch_bounds__(256) void prep_wall(
    const float* __restrict__ w1, const float* __restrict__ w2,
    const float* __restrict__ w3, const float* __restrict__ w4,
    const float* __restrict__ wd,
    unsigned short* __restrict__ Bt1, unsigned short* __restrict__ Bt2,
    unsigned short* __restrict__ Bt3, unsigned short* __restrict__ Bt4,
    unsigned short* __restrict__ Btd)
{
    int idx = blockIdx.x * 256 + threadIdx.x;
    if (idx < 16128)      pack_conv_w(w1, Bt1, idx,          196, 7,  64,  4);
    else if (idx < 20736) pack_conv_w(w2, Bt2, idx - 16128,   64, 2,  64,  4);
    else if (idx < 25344) pack_conv_w(w3, Bt3, idx - 20736,   64, 2,  64,  4);
    else if (idx < 41472) pack_conv_w(w4, Bt4, idx - 25344,   64, 2, 216, 14);
    else if (idx < 47616) {
        int id2 = idx - 41472;
        int lane = id2 & 63;
        int r = id2 >> 6;
        int nf = r % 4; r >>= 2;
        int ck = r % 3;
        int g  = r / 3;
        int n  = nf * 16 + (lane & 15);             // oc
        int kb = ck * 32 + (lane >> 4) * 8;
        short8 o;
        #pragma unroll
        for (int j = 0; j < 8; ++j) {
            int k = kb + j;
            int t = k >> 3, c = k & 7;
            float v = (t < 9) ? wd[((size_t)n * 64 + g * 8 + c) * 9 + t] : 0.f;
            o[j] = (short)f2bf(v);
        }
        *(short8*)(Btd + (size_t)id2 * 8) = o;
    }
}

// ---------------------------------------------------------------------------
// MFMA implicit-GEMM 3x3 conv, pad=1 (128-px blocks, wave = 32 px, triplet
// B-staging with 3 named prefetch regs) + XCD swizzle. (round-16 known good)
// ---------------------------------------------------------------------------
template<int KCH, int NFTOT, int NF, bool RELU>
__global__ __launch_bounds__(256) void conv_mfma(
    const unsigned short* __restrict__ X, const unsigned short* __restrict__ Bt,
    const float* __restrict__ bias, unsigned short* __restrict__ Y,
    int CoutTot, int fBase0)
{
    static_assert(NF == 4, "staging assumes 4 KB per tap chunk");
    __shared__ __align__(16) unsigned short bsh[3 * 2048];   // 12 KB

    const int tid  = threadIdx.x;
    const int lane = tid & 63;
    const int wv   = tid >> 6;
    const int m0   = swz960(blockIdx.x) * 128 + wv * 32;
    const int fBase = fBase0 + blockIdx.y * NF;
    const int lm = lane & 15;
    const int l16 = lane >> 4;

    int p[2], hh[2], wp[2];
    #pragma unroll
    for (int mf = 0; mf < 2; ++mf) {
        int pm = m0 + mf * 16 + lm;
        p[mf] = pm;
        hh[mf] = (pm / W_) % H_;
        wp[mf] = pm % W_;
    }

    f32x4 acc[2][NF];
    #pragma unroll
    for (int nf = 0; nf < NF; ++nf) {
        int oc = (fBase + nf) * 16 + lm;
        float bv = (oc < CoutTot) ? bias[oc] : 0.f;
        f32x4 a = {bv, bv, bv, bv};
        acc[0][nf] = a; acc[1][nf] = a;
    }

    const short8 zero = {0,0,0,0,0,0,0,0};
    constexpr int S3 = KCH * 3;          // triplet count

    uint4 bta = *(const uint4*)(Bt + ((size_t)(0 * KCH) * NFTOT + fBase) * 512 + tid * 8);
    uint4 btb = *(const uint4*)(Bt + ((size_t)(1 * KCH) * NFTOT + fBase) * 512 + tid * 8);
    uint4 btc = *(const uint4*)(Bt + ((size_t)(2 * KCH) * NFTOT + fBase) * 512 + tid * 8);

    for (int s3 = 0; s3 < S3; ++s3) {
        const int ck = s3 / 3, tb = (s3 % 3) * 3;
        __syncthreads();
        *(uint4*)(bsh + 0 * 2048 + tid * 8) = bta;
        *(uint4*)(bsh + 1 * 2048 + tid * 8) = btb;
        *(uint4*)(bsh + 2 * 2048 + tid * 8) = btc;
        __syncthreads();
        if (s3 + 1 < S3) {
            const int ck2 = (s3 + 1) / 3, tb2 = ((s3 + 1) % 3) * 3;
            bta = *(const uint4*)(Bt + ((size_t)((tb2 + 0) * KCH + ck2) * NFTOT + fBase) * 512 + tid * 8);
            btb = *(const uint4*)(Bt + ((size_t)((tb2 + 1) * KCH + ck2) * NFTOT + fBase) * 512 + tid * 8);
            btc = *(const uint4*)(Bt + ((size_t)((tb2 + 2) * KCH + ck2) * NFTOT + fBase) * 512 + tid * 8);
        }
        const unsigned short* Xp = X + (size_t)(ck * 4 + l16) * NPIX * 8;
        #pragma unroll
        for (int j = 0; j < 3; ++j) {
            const int t = tb + j;
            const int di = t / 3 - 1, dj = t % 3 - 1;
            short8 bfr[NF];
            #pragma unroll
            for (int nf = 0; nf < NF; ++nf)
                bfr[nf] = *(const short8*)(bsh + j * 2048 + nf * 512 + lane * 8);
            #pragma unroll
            for (int mf = 0; mf < 2; ++mf) {
                bool val = ((unsigned)(hh[mf] + di) < (unsigned)H_) &&
                           ((unsigned)(wp[mf] + dj) < (unsigned)W_);
                const unsigned short* ap = Xp + (size_t)(p[mf] + di * W_ + dj) * 8;
                short8 afr = val ? *(const short8*)ap : zero;
                #pragma unroll
                for (int nf = 0; nf < NF; ++nf)
                    acc[mf][nf] = __builtin_amdgcn_mfma_f32_16x16x32_bf16(
                        afr, bfr[nf], acc[mf][nf], 0, 0, 0);
            }
        }
    }

    const int prow = l16 * 4;
    #pragma unroll
    for (int mf = 0; mf < 2; ++mf)
        #pragma unroll
        for (int nf = 0; nf < NF; ++nf) {
            int oc = (fBase + nf) * 16 + lm;
            if (oc < CoutTot) {
                #pragma unroll
                for (int r = 0; r < 4; ++r) {
                    int pix = m0 + mf * 16 + prow + r;
                    float v = acc[mf][nf][r];
                    if (RELU) v = (v >= 0.f) ? v : 0.1f * v;
                    Y[((size_t)(oc >> 3) * NPIX + pix) * 8 + (oc & 7)] = f2bf(v);
                }
            }
        }
}

// ---------------------------------------------------------------------------
// conv4: ONE dispatch, grid (960, 2); FB = blockIdx.y*7. + XCD swizzle.
// (round-16 known good)
// ---------------------------------------------------------------------------
__global__ __launch_bounds__(256, 4) void conv4_mfma(
    const unsigned short* __restrict__ X, const unsigned short* __restrict__ Bt,
    const float* __restrict__ bias,
    unsigned short* __restrict__ oY, unsigned short* __restrict__ oX,
    unsigned short* __restrict__ oM)
{
    __shared__ __align__(16) unsigned short bsh[7 * 512];   // 7168 B

    const int tid  = threadIdx.x;
    const int lane = tid & 63;
    const int wv   = tid >> 6;
    const int pix0 = swz960(blockIdx.x) * 128;
    const int m0   = pix0 + wv * 32;
    const int lm = lane & 15;
    const int l16 = lane >> 4;
    const int FB = blockIdx.y * 7;         // frag base (block-uniform)

    int p[2], hh[2], wp[2];
    #pragma unroll
    for (int mf = 0; mf < 2; ++mf) {
        int pm = m0 + mf * 16 + lm;
        p[mf] = pm;
        hh[mf] = (pm / W_) % H_;
        wp[mf] = pm % W_;
    }

    f32x4 acc[2][7];
    #pragma unroll
    for (int nf = 0; nf < 7; ++nf) {
        int oc = (FB + nf) * 16 + lm;
        float bv = (oc < 216) ? bias[oc] : 0.f;
        f32x4 a = {bv, bv, bv, bv};
        acc[0][nf] = a; acc[1][nf] = a;
    }

    const short8 zero = {0,0,0,0,0,0,0,0};
    const bool two = (tid < 192);

    uint4 bt0 = *(const uint4*)(Bt + (size_t)FB * 512 + tid * 8);
    uint4 bt1 = {0u, 0u, 0u, 0u};
    if (two) bt1 = *(const uint4*)(Bt + (size_t)FB * 512 + (256 + tid) * 8);

    #pragma unroll
    for (int s = 0; s < 18; ++s) {
        const int ck = s / 9, t = s % 9;
        __syncthreads();
        *(uint4*)(bsh + tid * 8) = bt0;
        if (two) *(uint4*)(bsh + (256 + tid) * 8) = bt1;
        __syncthreads();
        if (s + 1 < 18) {
            const int ck2 = (s + 1) / 9, t2 = (s + 1) % 9;
            const unsigned short* nb =
                Bt + ((size_t)((t2 * 2 + ck2) * 14 + FB)) * 512;
            bt0 = *(const uint4*)(nb + tid * 8);
            if (two) bt1 = *(const uint4*)(nb + (256 + tid) * 8);
        }
        const int di = t / 3 - 1, dj = t % 3 - 1;
        const unsigned short* Xp = X + (size_t)(ck * 4 + l16) * NPIX * 8;
        short8 afr[2];
        #pragma unroll
        for (int mf = 0; mf < 2; ++mf) {
            bool val = ((unsigned)(hh[mf] + di) < (unsigned)H_) &&
                       ((unsigned)(wp[mf] + dj) < (unsigned)W_);
            const unsigned short* ap = Xp + (size_t)(p[mf] + di * W_ + dj) * 8;
            afr[mf] = val ? *(const short8*)ap : zero;
        }
        #pragma unroll
        for (int nf = 0; nf < 7; ++nf) {
            short8 bfr = *(const short8*)(bsh + nf * 512 + lane * 8);
            acc[0][nf] = __builtin_amdgcn_mfma_f32_16x16x32_bf16(
                afr[0], bfr, acc[0][nf], 0, 0, 0);
            acc[1][nf] = __builtin_amdgcn_mfma_f32_16x16x32_bf16(
                afr[1], bfr, acc[1][nf], 0, 0, 0);
        }
    }

    const int prow = l16 * 4;
    #pragma unroll
    for (int mf = 0; mf < 2; ++mf) {
        const int pixb = m0 + mf * 16 + prow;      // 4 consecutive pixels
        #pragma unroll
        for (int nf = 0; nf < 7; ++nf) {
            const int nfg = FB + nf;               // block-uniform
            const int oc = nfg * 16 + lm;
            if (nfg < 9) {
                const int pr = nfg * 8 + (lm >> 1);
                unsigned short* plane = ((lm & 1) ? oX : oY) + (size_t)pr * NPIX;
                uint2 sv;
                sv.x = cvt_pk_bf16(acc[mf][nf][0], acc[mf][nf][1]);
                sv.y = cvt_pk_bf16(acc[mf][nf][2], acc[mf][nf][3]);
                *(uint2*)(plane + pixb) = sv;
            } else if (oc < 216) {
                const int mi = (nfg - 9) * 16 + lm;
                float v0 = 1.f / (1.f + expf(-acc[mf][nf][0]));
                float v1 = 1.f / (1.f + expf(-acc[mf][nf][1]));
                float v2 = 1.f / (1.f + expf(-acc[mf][nf][2]));
                float v3 = 1.f / (1.f + expf(-acc[mf][nf][3]));
                uint2 sv;
                sv.x = cvt_pk_bf16(v0, v1);
                sv.y = cvt_pk_bf16(v2, v3);
                *(uint2*)(oM + (size_t)mi * NPIX + pixb) = sv;
            }
        }
    }
}

// ---------------------------------------------------------------------------
// Fused deformable conv — v20 = v19 (double-buffered LDS, one barrier/group)
// + T5 s_setprio(1) around the MFMA cluster (waves in different blocks are
// at different phases; MFMA-entering waves get scheduler priority over
// gather-issuing waves; the proven-positive setprio regime per m191).
// ---------------------------------------------------------------------------
__global__ __launch_bounds__(256) void deform_mfma(
    const unsigned short* __restrict__ Xg,   // [8][NPIX][8] bf16 planes (X1)
    const unsigned short* __restrict__ oY,   // [72][NPIX] bf16 raw dy
    const unsigned short* __restrict__ oX,   // [72][NPIX] bf16 raw dx
    const unsigned short* __restrict__ oM,   // [72][NPIX] bf16 sigmoid(mask)
    const float* __restrict__ f1, const float* __restrict__ f2,
    const unsigned short* __restrict__ Btd,  // [8][3][4][64][8] bf16
    const float* __restrict__ bia,           // 64
    float* __restrict__ out)                 // B,64,H,W fp32 NCHW
{
    __shared__ __align__(16) char lds[2 * 16384];   // 32 KB, two buffers

    const int tid  = threadIdx.x;             // 0..255
    const int lane = tid & 63;
    const int wv   = tid >> 6;                // 0..3
    const int lm   = lane & 15;
    const int l16  = lane >> 4;
    const int pix0 = blockIdx.x * 64;
    const int b    = pix0 / HW_;
    const int hw0  = pix0 % HW_;

    const int pix = tid & 63;
    const int hw  = hw0 + pix;
    const int h   = hw / W_;
    const int w   = hw - h * W_;
    const size_t gp = (size_t)(pix0 + pix);
    const size_t bF = (size_t)b * 2 * HW_;

    {
        uint4 z = {0u, 0u, 0u, 0u};
        #pragma unroll
        for (int i = 0; i < 8; ++i)
            ((uint4*)lds)[i * 256 + tid] = z;
    }

    f32x4 acc[4];            // wave's 16-oc slice (oc = wv*16+lm), 64 px
    {
        float bv = bia[wv * 16 + lm];
        f32x4 a = {bv, bv, bv, bv};
        #pragma unroll
        for (int mf = 0; mf < 4; ++mf) acc[mf] = a;
    }

    auto sample = [&](int g, char* buf) {
        const unsigned short* Xp = Xg + (size_t)g * NPIX * 8;
        const float* fl = (g < 4) ? f1 : f2;
        const float fy = fl[bF + (size_t)HW_ + hw];
        const float fx = fl[bF + hw];
        unsigned short uy[3], ux[3], um[3];
        #pragma unroll
        for (int it = 0; it < 3; ++it) {
            int t = wv + 4 * it;
            bool act = (it < 2) || (wv == 0);
            if (act) {
                size_t po = (size_t)(g * 9 + t) * NPIX + gp;
                uy[it] = oY[po]; ux[it] = oX[po]; um[it] = oM[po];
            }
        }
        #pragma unroll
        for (int it = 0; it < 3; ++it) {
            int t = wv + 4 * it;
            bool act = (it < 2) || (wv == 0);
            if (act) {
                float dy = bf2f(uy[it]) + fy;
                float dx = bf2f(ux[it]) + fx;
                float m  = bf2f(um[it]);

                float ys = dy + (float)(h - 1 + t / 3);
                float xs = dx + (float)(w - 1 + t % 3);
                float y0f = floorf(ys), x0f = floorf(xs);
                float wy1 = ys - y0f, wx1 = xs - x0f;
                float wy0 = 1.f - wy1, wx0 = 1.f - wx1;
                int iy0 = (int)y0f, ix0 = (int)x0f;
                int iy1 = iy0 + 1,  ix1 = ix0 + 1;
                bool vy0 = (unsigned)iy0 < (unsigned)H_;
                bool vy1 = (unsigned)iy1 < (unsigned)H_;
                bool vx0 = (unsigned)ix0 < (unsigned)W_;
                bool vx1 = (unsigned)ix1 < (unsigned)W_;
                int cy0 = min(max(iy0, 0), H_ - 1), cy1 = min(max(iy1, 0), H_ - 1);
                int cx0 = min(max(ix0, 0), W_ - 1), cx1 = min(max(ix1, 0), W_ - 1);
                float w00 = (vy0 && vx0) ? wy0 * wx0 * m : 0.f;
                float w01 = (vy0 && vx1) ? wy0 * wx1 * m : 0.f;
                float w10 = (vy1 && vx0) ? wy1 * wx0 * m : 0.f;
                float w11 = (vy1 && vx1) ? wy1 * wx1 * m : 0.f;

                size_t r0 = (size_t)b * HW_ + (size_t)cy0 * W_;
                size_t r1 = (size_t)b * HW_ + (size_t)cy1 * W_;
                uint4 c00 = *(const uint4*)(Xp + (r0 + cx0) * 8);
                uint4 c01 = *(const uint4*)(Xp + (r0 + cx1) * 8);
                uint4 c10 = *(const uint4*)(Xp + (r1 + cx0) * 8);
                uint4 c11 = *(const uint4*)(Xp + (r1 + cx1) * 8);

                float a8[8];
                #pragma unroll
                for (int i = 0; i < 8; ++i) a8[i] = 0.f;
                const unsigned int u00[4] = {c00.x, c00.y, c00.z, c00.w};
                const unsigned int u01[4] = {c01.x, c01.y, c01.z, c01.w};
                const unsigned int u10[4] = {c10.x, c10.y, c10.z, c10.w};
                const unsigned int u11[4] = {c11.x, c11.y, c11.z, c11.w};
                #pragma unroll
                for (int i = 0; i < 4; ++i) {
                    a8[2*i]   += w00 * __builtin_bit_cast(float, u00[i] << 16);
                    a8[2*i+1] += w00 * __builtin_bit_cast(float, u00[i] & 0xFFFF0000u);
                    a8[2*i]   += w01 * __builtin_bit_cast(float, u01[i] << 16);
                    a8[2*i+1] += w01 * __builtin_bit_cast(float, u01[i] & 0xFFFF0000u);
                    a8[2*i]   += w10 * __builtin_bit_cast(float, u10[i] << 16);
                    a8[2*i+1] += w10 * __builtin_bit_cast(float, u10[i] & 0xFFFF0000u);
                    a8[2*i]   += w11 * __builtin_bit_cast(float, u11[i] << 16);
                    a8[2*i+1] += w11 * __builtin_bit_cast(float, u11[i] & 0xFFFF0000u);
                }
                uint4 ov;
                ov.x = cvt_pk_bf16(a8[0], a8[1]);
                ov.y = cvt_pk_bf16(a8[2], a8[3]);
                ov.z = cvt_pk_bf16(a8[4], a8[5]);
                ov.w = cvt_pk_bf16(a8[6], a8[7]);
                int slot = t ^ (pix & 7);
                *(uint4*)(buf + pix * 256 + slot * 16) = ov;
            }
        }
    };

    __syncthreads();          // zero-init visible
    sample(0, lds);           // prologue: group 0 -> buffer 0
    __syncthreads();          // buffer 0 ready

    for (int g = 0; g < 8; ++g) {
        char* cur = lds + (g & 1) * 16384;
        char* nxt = lds + ((g + 1) & 1) * 16384;
        // issue next group's sampling first (overlaps with MFMA below)
        if (g < 7) sample(g + 1, nxt);
        // MFMA for current group from cur — T5: boost priority for the cluster
        __builtin_amdgcn_s_setprio(1);
        #pragma unroll
        for (int ck = 0; ck < 3; ++ck) {
            short8 bfr = ((const short8*)Btd)[((size_t)(g * 3 + ck) * 4 + wv) * 64 + lane];
            const int slotbase = ck * 4 + l16;
            #pragma unroll
            for (int mf = 0; mf < 4; ++mf) {
                int row = mf * 16 + lm;
                int slot = slotbase ^ (lm & 7);
                short8 afr = *(const short8*)(cur + row * 256 + slot * 16);
                acc[mf] = __builtin_amdgcn_mfma_f32_16x16x32_bf16(
                    afr, bfr, acc[mf], 0, 0, 0);
            }
        }
        __builtin_amdgcn_s_setprio(0);
        __syncthreads();      // cur reads done; nxt writes visible
    }

    const int oc = wv * 16 + lm;
    #pragma unroll
    for (int mf = 0; mf < 4; ++mf) {
        int px = hw0 + mf * 16 + l16 * 4;
        *(f32x4*)(out + (size_t)(b * 64 + oc) * HW_ + px) = acc[mf];
    }
}

// ---------------------------------------------------------------------------
extern "C" void kernel_launch(void* const* d_in, const int* in_sizes, int n_in,
                              void* d_out, int out_size, void* d_ws, size_t ws_size,
                              hipStream_t stream)
{
    const float* cfw  = (const float*)d_in[0];
    const float* fpro = (const float*)d_in[1];
    const float* fprv = (const float*)d_in[2];
    const float* fl1  = (const float*)d_in[3];
    const float* fl2  = (const float*)d_in[4];
    const float* w1   = (const float*)d_in[5];
    const float* b1   = (const float*)d_in[6];
    const float* w2   = (const float*)d_in[7];
    const float* b2   = (const float*)d_in[8];
    const float* w3   = (const float*)d_in[9];
    const float* b3   = (const float*)d_in[10];
    const float* w4   = (const float*)d_in[11];
    const float* b4   = (const float*)d_in[12];
    const float* wdef = (const float*)d_in[13];
    const float* bdef = (const float*)d_in[14];
    float* out = (float*)d_out;

    // ---- workspace layout (bytes) ----
    char* ws = (char*)d_ws;
    unsigned short* X1  = (unsigned short*)(ws);
    unsigned short* buf1= (unsigned short*)(ws + 55050240);   // o1 / o3
    unsigned short* o2  = (unsigned short*)(ws + 70778880);   // dead after conv3
    unsigned short* oY  = (unsigned short*)(ws + 70778880);   // clobbers o2 (OK)
    unsigned short* oX  = oY + (size_t)72 * NPIX;
    unsigned short* oM  = oX + (size_t)72 * NPIX;
    unsigned short* Bt1 = (unsigned short*)(ws + 125829120);
    unsigned short* Bt2 = (unsigned short*)(ws + 125829120 + 258048);
    unsigned short* Bt3 = (unsigned short*)(ws + 125829120 + 258048 + 73728);
    unsigned short* Bt4 = (unsigned short*)(ws + 125829120 + 258048 + 2*73728);
    unsigned short* Btd = (unsigned short*)(ws + 125829120 + 2*258048 + 2*73728);

    prep_x1<<<dim3(NPIX / 1024, 28), dim3(256), 0, stream>>>(
        cfw, fpro, fprv, fl1, fl2, X1);
    prep_wall<<<dim3((47616 + 255) / 256), dim3(256), 0, stream>>>(
        w1, w2, w3, w4, wdef, Bt1, Bt2, Bt3, Bt4, Btd);

    dim3 blk(256);
    dim3 gridM(NPIX / 128, 1);
    // conv1: X1(196) -> o1 (buf1), lrelu
    conv_mfma<7, 4, 4, true><<<gridM, blk, 0, stream>>>(X1, Bt1, b1, buf1, 64, 0);
    // conv2: o1 (buf1) -> o2, lrelu
    conv_mfma<2, 4, 4, true><<<gridM, blk, 0, stream>>>(buf1, Bt2, b2, o2, 64, 0);
    // conv3: o2 -> o3 (buf1, o1 dead), lrelu
    conv_mfma<2, 4, 4, true><<<gridM, blk, 0, stream>>>(o2, Bt3, b3, buf1, 64, 0);
    // conv4: o3 (buf1) -> channel-planar oY/oX/oM, ONE dispatch (y = half)
    conv4_mfma<<<dim3(NPIX / 128, 2), blk, 0, stream>>>(buf1, Bt4, b4, oY, oX, oM);
    // fused deformable conv: double-buffered LDS + setprio MFMA cluster
    deform_mfma<<<dim3(NPIX / 64), blk, 0, stream>>>(
        X1, oY, oX, oM, fl1, fl2, Btd, bdef, out);
}